// Round 5
// baseline (751.067 us; speedup 1.0000x reference)
//
#include <hip/hip_runtime.h>

typedef __attribute__((ext_vector_type(8))) short bf16x8;
typedef __attribute__((ext_vector_type(4))) float f32x4;
typedef __attribute__((ext_vector_type(4))) float f4v;

#define NU 150000
#define NI 50000
#define NTOT 200000
#define KU 524
#define KUP 576
#define KI 1292
#define KIP 1344

__device__ __forceinline__ f4v ld4nt(const float* p) {
    return __builtin_nontemporal_load((const f4v*)p);
}
__device__ __forceinline__ unsigned short bf16r(float x) {
    unsigned u = __float_as_uint(x);
    u += 0x7fff + ((u >> 16) & 1);
    return (unsigned short)(u >> 16);
}
__device__ __forceinline__ unsigned pk2(float lo, float hi) {
    unsigned a = __float_as_uint(lo), b = __float_as_uint(hi);
    a += 0x7fff + ((a >> 16) & 1);
    b += 0x7fff + ((b >> 16) & 1);
    return (a >> 16) | (b & 0xffff0000u);
}
__device__ __forceinline__ float bflo(unsigned s) { return __uint_as_float(s << 16); }
__device__ __forceinline__ float bfhi(unsigned s) { return __uint_as_float(s & 0xffff0000u); }

// accumulate 16 bf16 (32B) from p into s[0..15]
__device__ __forceinline__ void add16(float* s, const unsigned short* p) {
    const uint4 q0 = *(const uint4*)p;
    const uint4 q1 = *(const uint4*)(p + 8);
    s[0] += bflo(q0.x); s[1] += bfhi(q0.x); s[2] += bflo(q0.y); s[3] += bfhi(q0.y);
    s[4] += bflo(q0.z); s[5] += bfhi(q0.z); s[6] += bflo(q0.w); s[7] += bfhi(q0.w);
    s[8] += bflo(q1.x); s[9] += bfhi(q1.x); s[10] += bflo(q1.y); s[11] += bfhi(q1.y);
    s[12] += bflo(q1.z); s[13] += bfhi(q1.z); s[14] += bflo(q1.w); s[15] += bfhi(q1.w);
}

// W [K][64] fp32 -> WT [64][Kpad] bf16 (zero-padded K)
__global__ void prep_wt(const float* __restrict__ src, unsigned short* __restrict__ dst,
                        int K, int Kpad) {
    const int c = blockIdx.y;
    const int k = blockIdx.x * 256 + threadIdx.x;
    if (k >= Kpad) return;
    dst[(size_t)c * Kpad + k] = (k < K) ? bf16r(src[(size_t)k * 64 + c]) : (unsigned short)0;
}

// flat fp32 -> bf16 convert
__global__ void prep_cvt(const float* __restrict__ src, unsigned short* __restrict__ dst, int n) {
    const int i = blockIdx.x * 256 + threadIdx.x;
    if (i < n) dst[i] = bf16r(src[i]);
}

// ---------------------------------------------------------------------------
// Fused node-feature build + projection via MFMA. 64 rows/block, 4 waves.
// Streams (id/wordvec/sentence/numeric/idx) use non-temporal loads; gathers
// hit bf16 tables kept L2-resident. Pipeline: store(k) -> load(k+1) -> mfma(k).
// ---------------------------------------------------------------------------
__global__ __launch_bounds__(256, 6) void node_init_kernel(
    const float* __restrict__ id_emb, const unsigned short* __restrict__ ftab16,
    const unsigned short* __restrict__ wemb16, const float* __restrict__ numeric,
    const float* __restrict__ wordvec, const float* __restrict__ sentence,
    const int* __restrict__ feat_idx, const int* __restrict__ text_idx,
    const unsigned short* __restrict__ WT, const float* __restrict__ projb,
    const float* __restrict__ numW, const float* __restrict__ numb,
    unsigned short* __restrict__ x_out, int n, int Ktot, int Kpad, int row_off)
{
    __shared__ __align__(16) unsigned short aS[64][72];
    __shared__ unsigned short fiS[64][5];
    __shared__ unsigned short tiS[64][24];
    __shared__ float nmrS[64][10];

    const int t = threadIdx.x;
    const int row0 = blockIdx.x * 64;

    for (int e = t; e < 64 * 5; e += 256) {
        const int r = e / 5, j = e - r * 5, row = row0 + r;
        fiS[r][j] = (row < n) ? (unsigned short)__builtin_nontemporal_load(feat_idx + row * 5 + j)
                              : (unsigned short)0;
    }
    for (int e = t; e < 64 * 24; e += 256) {
        const int r = e / 24, j = e - r * 24, row = row0 + r;
        tiS[r][j] = (row < n) ? (unsigned short)__builtin_nontemporal_load(text_idx + row * 24 + j)
                              : (unsigned short)0;
    }
    for (int e = t; e < 64 * 10; e += 256) {
        const int r = e / 10, j = e - r * 10, row = row0 + r;
        nmrS[r][j] = (row < n) ? __builtin_nontemporal_load(numeric + (size_t)row * 10 + j) : 0.f;
    }
    __syncthreads();

    const int sr  = t >> 2;            // staging row
    const int scq = (t & 3) * 16;      // staging col chunk (floats)
    const int srow = row0 + sr;
    const bool svalid = srow < n;

    const int lane = t & 63;
    const int w16 = (t >> 6) * 16;
    const int l15 = lane & 15;
    const int hi8 = (lane >> 4) * 8;
    const int g4  = (lane >> 4) * 4;

    f32x4 acc[4];
    #pragma unroll
    for (int ct = 0; ct < 4; ++ct) acc[ct] = (f32x4){0.f, 0.f, 0.f, 0.f};

    f4v vals[4];
    auto load_tile = [&](int kt) {
        const int k16 = kt * 64 + scq;
        if (svalid && k16 >= 64 && k16 < 224) {
            // whole 16-col chunk inside one gather segment (boundaries are x16)
            float s[16];
            #pragma unroll
            for (int i = 0; i < 16; ++i) s[i] = 0.f;
            if (k16 < 128) {
                const int c = k16 - 64;
                #pragma unroll
                for (int m = 0; m < 5; ++m)
                    add16(s, ftab16 + (size_t)fiS[sr][m] * 64 + c);
                #pragma unroll
                for (int i = 0; i < 16; ++i) s[i] *= 0.2f;
            } else {
                const int k2 = k16 - 128;
                const int f = k2 >> 5, c = k2 & 31;
                #pragma unroll
                for (int m = 0; m < 8; ++m)
                    add16(s, wemb16 + (size_t)tiS[sr][f * 8 + m] * 32 + c);
                #pragma unroll
                for (int i = 0; i < 16; ++i) s[i] *= 0.125f;
            }
            #pragma unroll
            for (int j = 0; j < 4; ++j)
                vals[j] = (f4v){s[4 * j], s[4 * j + 1], s[4 * j + 2], s[4 * j + 3]};
        } else {
            #pragma unroll
            for (int j = 0; j < 4; ++j) {
                const int k4 = k16 + j * 4;
                f4v v = (f4v){0.f, 0.f, 0.f, 0.f};
                if (svalid && k4 < Ktot) {
                    if (k4 >= 524)      v = ld4nt(sentence + (size_t)srow * 768 + (k4 - 524));
                    else if (k4 >= 224) v = ld4nt(wordvec + (size_t)srow * 300 + (k4 - 224));
                    else                v = ld4nt(id_emb + (size_t)srow * 64 + k4);
                }
                vals[j] = v;
            }
        }
    };

    const int NT = Kpad / 64;
    load_tile(0);
    for (int kt = 0; kt < NT; ++kt) {
        __syncthreads();   // previous tile's MFMA readers done
        #pragma unroll
        for (int j = 0; j < 2; ++j) {
            const f4v a0 = vals[2 * j], a1 = vals[2 * j + 1];
            uint4 pk;
            pk.x = pk2(a0.x, a0.y); pk.y = pk2(a0.z, a0.w);
            pk.z = pk2(a1.x, a1.y); pk.w = pk2(a1.z, a1.w);
            *(uint4*)&aS[sr][scq + j * 8] = pk;
        }
        __syncthreads();   // tile visible
        if (kt + 1 < NT) load_tile(kt + 1);   // prefetch, hidden under MFMA
        #pragma unroll
        for (int ks = 0; ks < 2; ++ks) {
            const bf16x8 af = *(const bf16x8*)&aS[w16 + l15][ks * 32 + hi8];
            #pragma unroll
            for (int ct = 0; ct < 4; ++ct) {
                const bf16x8 bfr = *(const bf16x8*)&WT[(size_t)(ct * 16 + l15) * Kpad
                                                      + kt * 64 + ks * 32 + hi8];
                acc[ct] = __builtin_amdgcn_mfma_f32_16x16x32_bf16(af, bfr, acc[ct], 0, 0, 0);
            }
        }
    }

    // epilogue: proj bias + numeric side-GEMM + num bias, write bf16 (nt)
    #pragma unroll
    for (int ct = 0; ct < 4; ++ct) {
        const int c = ct * 16 + l15;
        const float pb = projb[c] + numb[c];
        float wn[10];
        #pragma unroll
        for (int m = 0; m < 10; ++m) wn[m] = numW[m * 64 + c];
        #pragma unroll
        for (int j = 0; j < 4; ++j) {
            const int r = w16 + g4 + j;
            const int row = row0 + r;
            if (row < n) {
                float s = acc[ct][j] + pb;
                #pragma unroll
                for (int m = 0; m < 10; ++m) s += nmrS[r][m] * wn[m];
                __builtin_nontemporal_store(bf16r(s),
                    x_out + (size_t)(row_off + row) * 64 + c);
            }
        }
    }
}

// ---------------------------------------------------------------------------
// GNN layer via MFMA. 64 rows/block. nm(bf16 LDS) -> agg MFMA -> ag(LDS) ->
// out = [x | ag] @ W2 (x A-frags read directly from global bf16).
// ---------------------------------------------------------------------------
__global__ __launch_bounds__(256, 6) void gnn_layer_kernel(
    const unsigned short* __restrict__ x, const int* __restrict__ nbr,
    const unsigned short* __restrict__ VT, const unsigned short* __restrict__ W2T,
    const float* __restrict__ vb, const float* __restrict__ wb,
    void* __restrict__ outp, int finalize)
{
    __shared__ __align__(16) unsigned short mS[64][72];
    __shared__ int nbs[64][8];
    const int t = threadIdx.x;
    const int row0 = blockIdx.x * 64;

    for (int e = t; e < 512; e += 256)
        nbs[e >> 3][e & 7] = __builtin_nontemporal_load(nbr + row0 * 8 + e);
    __syncthreads();

    {   // neighbor mean -> mS (bf16)
        const int r = t >> 2, c16 = (t & 3) * 16;
        float s[16];
        #pragma unroll
        for (int i = 0; i < 16; ++i) s[i] = 0.f;
        #pragma unroll
        for (int m = 0; m < 8; ++m)
            add16(s, x + (size_t)nbs[r][m] * 64 + c16);
        uint4 o0, o1;
        o0.x = pk2(s[0] * 0.125f, s[1] * 0.125f);
        o0.y = pk2(s[2] * 0.125f, s[3] * 0.125f);
        o0.z = pk2(s[4] * 0.125f, s[5] * 0.125f);
        o0.w = pk2(s[6] * 0.125f, s[7] * 0.125f);
        o1.x = pk2(s[8] * 0.125f, s[9] * 0.125f);
        o1.y = pk2(s[10] * 0.125f, s[11] * 0.125f);
        o1.z = pk2(s[12] * 0.125f, s[13] * 0.125f);
        o1.w = pk2(s[14] * 0.125f, s[15] * 0.125f);
        *(uint4*)&mS[r][c16] = o0;
        *(uint4*)&mS[r][c16 + 8] = o1;
    }
    __syncthreads();

    const int lane = t & 63;
    const int w16 = (t >> 6) * 16;
    const int l15 = lane & 15;
    const int hi8 = (lane >> 4) * 8;
    const int g4  = (lane >> 4) * 4;

    // agg = nm @ vW
    f32x4 ag[4];
    #pragma unroll
    for (int ct = 0; ct < 4; ++ct) ag[ct] = (f32x4){0.f, 0.f, 0.f, 0.f};
    #pragma unroll
    for (int ks = 0; ks < 2; ++ks) {
        const bf16x8 af = *(const bf16x8*)&mS[w16 + l15][ks * 32 + hi8];
        #pragma unroll
        for (int ct = 0; ct < 4; ++ct) {
            const bf16x8 bfr = *(const bf16x8*)&VT[(ct * 16 + l15) * 64 + ks * 32 + hi8];
            ag[ct] = __builtin_amdgcn_mfma_f32_16x16x32_bf16(af, bfr, ag[ct], 0, 0, 0);
        }
    }
    __syncthreads();   // nm readers done
    #pragma unroll
    for (int ct = 0; ct < 4; ++ct) {
        const int c = ct * 16 + l15;
        const float b = vb[c];
        #pragma unroll
        for (int j = 0; j < 4; ++j)
            mS[w16 + g4 + j][c] = bf16r(ag[ct][j] + b);
    }
    __syncthreads();

    // out = [x | ag] @ wW
    f32x4 acc[4];
    #pragma unroll
    for (int ct = 0; ct < 4; ++ct) acc[ct] = (f32x4){0.f, 0.f, 0.f, 0.f};
    #pragma unroll
    for (int ks = 0; ks < 4; ++ks) {
        bf16x8 af;
        if (ks < 2) af = *(const bf16x8*)&x[(size_t)(row0 + w16 + l15) * 64 + ks * 32 + hi8];
        else        af = *(const bf16x8*)&mS[w16 + l15][(ks - 2) * 32 + hi8];
        #pragma unroll
        for (int ct = 0; ct < 4; ++ct) {
            const bf16x8 bfr = *(const bf16x8*)&W2T[(ct * 16 + l15) * 128 + ks * 32 + hi8];
            acc[ct] = __builtin_amdgcn_mfma_f32_16x16x32_bf16(af, bfr, acc[ct], 0, 0, 0);
        }
    }

    if (!finalize) {
        unsigned short* xo = (unsigned short*)outp;
        #pragma unroll
        for (int ct = 0; ct < 4; ++ct) {
            const int c = ct * 16 + l15;
            const float b = wb[c];
            #pragma unroll
            for (int j = 0; j < 4; ++j)
                __builtin_nontemporal_store(bf16r(fmaxf(acc[ct][j] + b, 0.f)),
                    xo + (size_t)(row0 + w16 + g4 + j) * 64 + c);
        }
    } else {
        float* fo = (float*)outp;
        float vc[4][4], ss[4];
        #pragma unroll
        for (int j = 0; j < 4; ++j) ss[j] = 0.f;
        #pragma unroll
        for (int ct = 0; ct < 4; ++ct) {
            const float b = wb[ct * 16 + l15];
            #pragma unroll
            for (int j = 0; j < 4; ++j) {
                vc[ct][j] = acc[ct][j] + b;
                ss[j] += vc[ct][j] * vc[ct][j];
            }
        }
        #pragma unroll
        for (int m = 1; m < 16; m <<= 1) {
            #pragma unroll
            for (int j = 0; j < 4; ++j) ss[j] += __shfl_xor(ss[j], m, 64);
        }
        #pragma unroll
        for (int j = 0; j < 4; ++j) ss[j] = 1.f / fmaxf(sqrtf(ss[j]), 1e-12f);
        #pragma unroll
        for (int ct = 0; ct < 4; ++ct) {
            const int c = ct * 16 + l15;
            #pragma unroll
            for (int j = 0; j < 4; ++j)
                __builtin_nontemporal_store(vc[ct][j] * ss[j],
                    fo + (size_t)(row0 + w16 + g4 + j) * 64 + c);
        }
    }
}

extern "C" void kernel_launch(void* const* d_in, const int* in_sizes, int n_in,
                              void* d_out, int out_size, void* d_ws, size_t ws_size,
                              hipStream_t stream) {
    const float* user_id_emb        = (const float*)d_in[0];
    const float* item_id_emb        = (const float*)d_in[1];
    const float* user_feat_table    = (const float*)d_in[2];
    const float* item_feat_table    = (const float*)d_in[3];
    const float* word_emb           = (const float*)d_in[4];
    const float* user_numeric       = (const float*)d_in[5];
    const float* item_numeric       = (const float*)d_in[6];
    const float* user_word_embedding= (const float*)d_in[7];
    const float* item_word_embedding= (const float*)d_in[8];
    const float* item_sentence_emb  = (const float*)d_in[9];
    const float* user_num_W         = (const float*)d_in[10];
    const float* user_num_b         = (const float*)d_in[11];
    const float* item_num_W         = (const float*)d_in[12];
    const float* item_num_b         = (const float*)d_in[13];
    const float* user_proj_W        = (const float*)d_in[14];
    const float* user_proj_b        = (const float*)d_in[15];
    const float* item_proj_W        = (const float*)d_in[16];
    const float* item_proj_b        = (const float*)d_in[17];
    const float* w_W                = (const float*)d_in[18];
    const float* w_b                = (const float*)d_in[19];
    const float* v_W                = (const float*)d_in[20];
    const float* v_b                = (const float*)d_in[21];
    const int*   user_feat_idx      = (const int*)d_in[22];
    const int*   item_feat_idx      = (const int*)d_in[23];
    const int*   user_text_idx      = (const int*)d_in[24];
    const int*   item_text_idx      = (const int*)d_in[25];
    const int*   neighbors          = (const int*)d_in[26];

    // ws layout (bf16): x0 [NTOT][64], x1 [NTOT][64]  (fits exactly in SZ*4 bytes)
    unsigned short* x0 = (unsigned short*)d_ws;
    unsigned short* x1 = x0 + (size_t)NTOT * 64;

    // scratch in d_out tail: weights + bf16 gather tables (consumed before the
    // final layer overwrites d_out; init/L0 never write d_out)
    const size_t tail_elems = (size_t)64 * (KUP + KIP + 64 + 128)   // WTs
                            + 30000 * 32 + 5000 * 64 + 10000 * 64;  // tables
    char* tail = (char*)d_out + (size_t)out_size * 4 - tail_elems * 2;
    unsigned short* WTu  = (unsigned short*)tail;
    unsigned short* WTi  = WTu + 64 * KUP;
    unsigned short* VT0  = WTi + 64 * KIP;
    unsigned short* W20  = VT0 + 64 * 64;
    unsigned short* we16 = W20 + 64 * 128;
    unsigned short* ftu16= we16 + 30000 * 32;
    unsigned short* fti16= ftu16 + 5000 * 64;
    // layer-1 weights re-prepped into dead x0 region after L0
    unsigned short* VT1 = (unsigned short*)d_ws;
    unsigned short* W21 = VT1 + 64 * 64;

    prep_wt<<<dim3((KUP + 255) / 256, 64), 256, 0, stream>>>(user_proj_W, WTu, KU, KUP);
    prep_wt<<<dim3((KIP + 255) / 256, 64), 256, 0, stream>>>(item_proj_W, WTi, KI, KIP);
    prep_wt<<<dim3(1, 64), 256, 0, stream>>>(v_W, VT0, 64, 64);
    prep_wt<<<dim3(1, 64), 256, 0, stream>>>(w_W, W20, 128, 128);
    prep_cvt<<<(30000 * 32 + 255) / 256, 256, 0, stream>>>(word_emb, we16, 30000 * 32);
    prep_cvt<<<(5000 * 64 + 255) / 256, 256, 0, stream>>>(user_feat_table, ftu16, 5000 * 64);
    prep_cvt<<<(10000 * 64 + 255) / 256, 256, 0, stream>>>(item_feat_table, fti16, 10000 * 64);

    node_init_kernel<<<(NU + 63) / 64, 256, 0, stream>>>(
        user_id_emb, ftu16, we16, user_numeric,
        user_word_embedding, nullptr, user_feat_idx, user_text_idx,
        WTu, user_proj_b, user_num_W, user_num_b, x0, NU, KU, KUP, 0);
    node_init_kernel<<<(NI + 63) / 64, 256, 0, stream>>>(
        item_id_emb, fti16, we16, item_numeric,
        item_word_embedding, item_sentence_emb, item_feat_idx, item_text_idx,
        WTi, item_proj_b, item_num_W, item_num_b, x0, NI, KI, KIP, NU);

    // layer 0: x0 -> x1 (relu, bf16)
    gnn_layer_kernel<<<NTOT / 64, 256, 0, stream>>>(
        x0, neighbors, VT0, W20, v_b, w_b, x1, 0);

    // re-prep layer-1 weights into dead x0 region
    prep_wt<<<dim3(1, 64), 256, 0, stream>>>(v_W + 64 * 64, VT1, 64, 64);
    prep_wt<<<dim3(1, 64), 256, 0, stream>>>(w_W + 128 * 64, W21, 128, 128);

    // layer 1 + fused normalize: x1 -> d_out (fp32)
    gnn_layer_kernel<<<NTOT / 64, 256, 0, stream>>>(
        x1, neighbors, VT1, W21, v_b + 64, w_b + 64, d_out, 1);
}

// Round 6
// 742.645 us; speedup vs baseline: 1.0113x; 1.0113x over previous
//
#include <hip/hip_runtime.h>

typedef __attribute__((ext_vector_type(8))) short bf16x8;
typedef __attribute__((ext_vector_type(4))) float f32x4;
typedef __attribute__((ext_vector_type(4))) float f4v;

#define NU 150000
#define NI 50000
#define NTOT 200000
#define KU 524
#define KUP 576
#define KI 1292
#define KIP 1344

__device__ __forceinline__ f4v ld4nt(const float* p) {
    return __builtin_nontemporal_load((const f4v*)p);
}
__device__ __forceinline__ unsigned short bf16r(float x) {
    unsigned u = __float_as_uint(x);
    u += 0x7fff + ((u >> 16) & 1);
    return (unsigned short)(u >> 16);
}
__device__ __forceinline__ unsigned pk2(float lo, float hi) {
    unsigned a = __float_as_uint(lo), b = __float_as_uint(hi);
    a += 0x7fff + ((a >> 16) & 1);
    b += 0x7fff + ((b >> 16) & 1);
    return (a >> 16) | (b & 0xffff0000u);
}
__device__ __forceinline__ float bflo(unsigned s) { return __uint_as_float(s << 16); }
__device__ __forceinline__ float bfhi(unsigned s) { return __uint_as_float(s & 0xffff0000u); }

// accumulate 16 bf16 (32B) from p into s[0..15]
__device__ __forceinline__ void add16(float* s, const unsigned short* p) {
    const uint4 q0 = *(const uint4*)p;
    const uint4 q1 = *(const uint4*)(p + 8);
    s[0] += bflo(q0.x); s[1] += bfhi(q0.x); s[2] += bflo(q0.y); s[3] += bfhi(q0.y);
    s[4] += bflo(q0.z); s[5] += bfhi(q0.z); s[6] += bflo(q0.w); s[7] += bfhi(q0.w);
    s[8] += bflo(q1.x); s[9] += bfhi(q1.x); s[10] += bflo(q1.y); s[11] += bfhi(q1.y);
    s[12] += bflo(q1.z); s[13] += bfhi(q1.z); s[14] += bflo(q1.w); s[15] += bfhi(q1.w);
}

// W [K][64] fp32 -> WT [64][Kpad] bf16 (zero-padded K)
__global__ void prep_wt(const float* __restrict__ src, unsigned short* __restrict__ dst,
                        int K, int Kpad) {
    const int c = blockIdx.y;
    const int k = blockIdx.x * 256 + threadIdx.x;
    if (k >= Kpad) return;
    dst[(size_t)c * Kpad + k] = (k < K) ? bf16r(src[(size_t)k * 64 + c]) : (unsigned short)0;
}

// flat fp32 -> bf16 convert
__global__ void prep_cvt(const float* __restrict__ src, unsigned short* __restrict__ dst, int n) {
    const int i = blockIdx.x * 256 + threadIdx.x;
    if (i < n) dst[i] = bf16r(src[i]);
}

// ---------------------------------------------------------------------------
// Fused node-feature build + projection via MFMA. 64 rows/block, 4 waves.
// Streams (id/wordvec/sentence/numeric/idx) use non-temporal LOADS (protect
// table L2 residency); all STORES are normal cached stores (L2 write-combine
// -- nt stores of partial lines caused 16x write amplification in R4).
// ---------------------------------------------------------------------------
__global__ __launch_bounds__(256, 6) void node_init_kernel(
    const float* __restrict__ id_emb, const unsigned short* __restrict__ ftab16,
    const unsigned short* __restrict__ wemb16, const float* __restrict__ numeric,
    const float* __restrict__ wordvec, const float* __restrict__ sentence,
    const int* __restrict__ feat_idx, const int* __restrict__ text_idx,
    const unsigned short* __restrict__ WT, const float* __restrict__ projb,
    const float* __restrict__ numW, const float* __restrict__ numb,
    unsigned short* __restrict__ x_out, int n, int Ktot, int Kpad, int row_off)
{
    __shared__ __align__(16) unsigned short aS[64][72];
    __shared__ unsigned short fiS[64][5];
    __shared__ unsigned short tiS[64][24];
    __shared__ float nmrS[64][10];

    const int t = threadIdx.x;
    const int row0 = blockIdx.x * 64;

    for (int e = t; e < 64 * 5; e += 256) {
        const int r = e / 5, j = e - r * 5, row = row0 + r;
        fiS[r][j] = (row < n) ? (unsigned short)__builtin_nontemporal_load(feat_idx + row * 5 + j)
                              : (unsigned short)0;
    }
    for (int e = t; e < 64 * 24; e += 256) {
        const int r = e / 24, j = e - r * 24, row = row0 + r;
        tiS[r][j] = (row < n) ? (unsigned short)__builtin_nontemporal_load(text_idx + row * 24 + j)
                              : (unsigned short)0;
    }
    for (int e = t; e < 64 * 10; e += 256) {
        const int r = e / 10, j = e - r * 10, row = row0 + r;
        nmrS[r][j] = (row < n) ? __builtin_nontemporal_load(numeric + (size_t)row * 10 + j) : 0.f;
    }
    __syncthreads();

    const int sr  = t >> 2;            // staging row
    const int scq = (t & 3) * 16;      // staging col chunk (floats)
    const int srow = row0 + sr;
    const bool svalid = srow < n;

    const int lane = t & 63;
    const int w16 = (t >> 6) * 16;
    const int l15 = lane & 15;
    const int hi8 = (lane >> 4) * 8;
    const int g4  = (lane >> 4) * 4;

    f32x4 acc[4];
    #pragma unroll
    for (int ct = 0; ct < 4; ++ct) acc[ct] = (f32x4){0.f, 0.f, 0.f, 0.f};

    f4v vals[4];
    auto load_tile = [&](int kt) {
        const int k16 = kt * 64 + scq;
        if (svalid && k16 >= 64 && k16 < 224) {
            // whole 16-col chunk inside one gather segment (boundaries are x16)
            float s[16];
            #pragma unroll
            for (int i = 0; i < 16; ++i) s[i] = 0.f;
            if (k16 < 128) {
                const int c = k16 - 64;
                #pragma unroll
                for (int m = 0; m < 5; ++m)
                    add16(s, ftab16 + (size_t)fiS[sr][m] * 64 + c);
                #pragma unroll
                for (int i = 0; i < 16; ++i) s[i] *= 0.2f;
            } else {
                const int k2 = k16 - 128;
                const int f = k2 >> 5, c = k2 & 31;
                #pragma unroll
                for (int m = 0; m < 8; ++m)
                    add16(s, wemb16 + (size_t)tiS[sr][f * 8 + m] * 32 + c);
                #pragma unroll
                for (int i = 0; i < 16; ++i) s[i] *= 0.125f;
            }
            #pragma unroll
            for (int j = 0; j < 4; ++j)
                vals[j] = (f4v){s[4 * j], s[4 * j + 1], s[4 * j + 2], s[4 * j + 3]};
        } else {
            #pragma unroll
            for (int j = 0; j < 4; ++j) {
                const int k4 = k16 + j * 4;
                f4v v = (f4v){0.f, 0.f, 0.f, 0.f};
                if (svalid && k4 < Ktot) {
                    if (k4 >= 524)      v = ld4nt(sentence + (size_t)srow * 768 + (k4 - 524));
                    else if (k4 >= 224) v = ld4nt(wordvec + (size_t)srow * 300 + (k4 - 224));
                    else                v = ld4nt(id_emb + (size_t)srow * 64 + k4);
                }
                vals[j] = v;
            }
        }
    };

    const int NT = Kpad / 64;
    load_tile(0);
    for (int kt = 0; kt < NT; ++kt) {
        __syncthreads();   // previous tile's MFMA readers done
        #pragma unroll
        for (int j = 0; j < 2; ++j) {
            const f4v a0 = vals[2 * j], a1 = vals[2 * j + 1];
            uint4 pk;
            pk.x = pk2(a0.x, a0.y); pk.y = pk2(a0.z, a0.w);
            pk.z = pk2(a1.x, a1.y); pk.w = pk2(a1.z, a1.w);
            *(uint4*)&aS[sr][scq + j * 8] = pk;
        }
        __syncthreads();   // tile visible
        if (kt + 1 < NT) load_tile(kt + 1);   // prefetch, hidden under MFMA
        #pragma unroll
        for (int ks = 0; ks < 2; ++ks) {
            const bf16x8 af = *(const bf16x8*)&aS[w16 + l15][ks * 32 + hi8];
            #pragma unroll
            for (int ct = 0; ct < 4; ++ct) {
                const bf16x8 bfr = *(const bf16x8*)&WT[(size_t)(ct * 16 + l15) * Kpad
                                                      + kt * 64 + ks * 32 + hi8];
                acc[ct] = __builtin_amdgcn_mfma_f32_16x16x32_bf16(af, bfr, acc[ct], 0, 0, 0);
            }
        }
    }

    // epilogue: proj bias + numeric side-GEMM + num bias, write bf16 (cached)
    #pragma unroll
    for (int ct = 0; ct < 4; ++ct) {
        const int c = ct * 16 + l15;
        const float pb = projb[c] + numb[c];
        float wn[10];
        #pragma unroll
        for (int m = 0; m < 10; ++m) wn[m] = numW[m * 64 + c];
        #pragma unroll
        for (int j = 0; j < 4; ++j) {
            const int r = w16 + g4 + j;
            const int row = row0 + r;
            if (row < n) {
                float s = acc[ct][j] + pb;
                #pragma unroll
                for (int m = 0; m < 10; ++m) s += nmrS[r][m] * wn[m];
                x_out[(size_t)(row_off + row) * 64 + c] = bf16r(s);
            }
        }
    }
}

// ---------------------------------------------------------------------------
// GNN layer via MFMA. 64 rows/block. nm(bf16 LDS) -> agg MFMA -> ag(LDS) ->
// out = [x | ag] @ W2 (x A-frags read directly from global bf16).
// ---------------------------------------------------------------------------
__global__ __launch_bounds__(256, 6) void gnn_layer_kernel(
    const unsigned short* __restrict__ x, const int* __restrict__ nbr,
    const unsigned short* __restrict__ VT, const unsigned short* __restrict__ W2T,
    const float* __restrict__ vb, const float* __restrict__ wb,
    void* __restrict__ outp, int finalize)
{
    __shared__ __align__(16) unsigned short mS[64][72];
    __shared__ int nbs[64][8];
    const int t = threadIdx.x;
    const int row0 = blockIdx.x * 64;

    for (int e = t; e < 512; e += 256)
        nbs[e >> 3][e & 7] = __builtin_nontemporal_load(nbr + row0 * 8 + e);
    __syncthreads();

    {   // neighbor mean -> mS (bf16)
        const int r = t >> 2, c16 = (t & 3) * 16;
        float s[16];
        #pragma unroll
        for (int i = 0; i < 16; ++i) s[i] = 0.f;
        #pragma unroll
        for (int m = 0; m < 8; ++m)
            add16(s, x + (size_t)nbs[r][m] * 64 + c16);
        uint4 o0, o1;
        o0.x = pk2(s[0] * 0.125f, s[1] * 0.125f);
        o0.y = pk2(s[2] * 0.125f, s[3] * 0.125f);
        o0.z = pk2(s[4] * 0.125f, s[5] * 0.125f);
        o0.w = pk2(s[6] * 0.125f, s[7] * 0.125f);
        o1.x = pk2(s[8] * 0.125f, s[9] * 0.125f);
        o1.y = pk2(s[10] * 0.125f, s[11] * 0.125f);
        o1.z = pk2(s[12] * 0.125f, s[13] * 0.125f);
        o1.w = pk2(s[14] * 0.125f, s[15] * 0.125f);
        *(uint4*)&mS[r][c16] = o0;
        *(uint4*)&mS[r][c16 + 8] = o1;
    }
    __syncthreads();

    const int lane = t & 63;
    const int w16 = (t >> 6) * 16;
    const int l15 = lane & 15;
    const int hi8 = (lane >> 4) * 8;
    const int g4  = (lane >> 4) * 4;

    // agg = nm @ vW
    f32x4 ag[4];
    #pragma unroll
    for (int ct = 0; ct < 4; ++ct) ag[ct] = (f32x4){0.f, 0.f, 0.f, 0.f};
    #pragma unroll
    for (int ks = 0; ks < 2; ++ks) {
        const bf16x8 af = *(const bf16x8*)&mS[w16 + l15][ks * 32 + hi8];
        #pragma unroll
        for (int ct = 0; ct < 4; ++ct) {
            const bf16x8 bfr = *(const bf16x8*)&VT[(ct * 16 + l15) * 64 + ks * 32 + hi8];
            ag[ct] = __builtin_amdgcn_mfma_f32_16x16x32_bf16(af, bfr, ag[ct], 0, 0, 0);
        }
    }
    __syncthreads();   // nm readers done
    #pragma unroll
    for (int ct = 0; ct < 4; ++ct) {
        const int c = ct * 16 + l15;
        const float b = vb[c];
        #pragma unroll
        for (int j = 0; j < 4; ++j)
            mS[w16 + g4 + j][c] = bf16r(ag[ct][j] + b);
    }
    __syncthreads();

    // out = [x | ag] @ wW
    f32x4 acc[4];
    #pragma unroll
    for (int ct = 0; ct < 4; ++ct) acc[ct] = (f32x4){0.f, 0.f, 0.f, 0.f};
    #pragma unroll
    for (int ks = 0; ks < 4; ++ks) {
        bf16x8 af;
        if (ks < 2) af = *(const bf16x8*)&x[(size_t)(row0 + w16 + l15) * 64 + ks * 32 + hi8];
        else        af = *(const bf16x8*)&mS[w16 + l15][(ks - 2) * 32 + hi8];
        #pragma unroll
        for (int ct = 0; ct < 4; ++ct) {
            const bf16x8 bfr = *(const bf16x8*)&W2T[(ct * 16 + l15) * 128 + ks * 32 + hi8];
            acc[ct] = __builtin_amdgcn_mfma_f32_16x16x32_bf16(af, bfr, acc[ct], 0, 0, 0);
        }
    }

    if (!finalize) {
        unsigned short* xo = (unsigned short*)outp;
        #pragma unroll
        for (int ct = 0; ct < 4; ++ct) {
            const int c = ct * 16 + l15;
            const float b = wb[c];
            #pragma unroll
            for (int j = 0; j < 4; ++j)
                xo[(size_t)(row0 + w16 + g4 + j) * 64 + c] = bf16r(fmaxf(acc[ct][j] + b, 0.f));
        }
    } else {
        float* fo = (float*)outp;
        float vc[4][4], ss[4];
        #pragma unroll
        for (int j = 0; j < 4; ++j) ss[j] = 0.f;
        #pragma unroll
        for (int ct = 0; ct < 4; ++ct) {
            const float b = wb[ct * 16 + l15];
            #pragma unroll
            for (int j = 0; j < 4; ++j) {
                vc[ct][j] = acc[ct][j] + b;
                ss[j] += vc[ct][j] * vc[ct][j];
            }
        }
        #pragma unroll
        for (int m = 1; m < 16; m <<= 1) {
            #pragma unroll
            for (int j = 0; j < 4; ++j) ss[j] += __shfl_xor(ss[j], m, 64);
        }
        #pragma unroll
        for (int j = 0; j < 4; ++j) ss[j] = 1.f / fmaxf(sqrtf(ss[j]), 1e-12f);
        #pragma unroll
        for (int ct = 0; ct < 4; ++ct) {
            const int c = ct * 16 + l15;
            #pragma unroll
            for (int j = 0; j < 4; ++j)
                fo[(size_t)(row0 + w16 + g4 + j) * 64 + c] = vc[ct][j] * ss[j];
        }
    }
}

extern "C" void kernel_launch(void* const* d_in, const int* in_sizes, int n_in,
                              void* d_out, int out_size, void* d_ws, size_t ws_size,
                              hipStream_t stream) {
    const float* user_id_emb        = (const float*)d_in[0];
    const float* item_id_emb        = (const float*)d_in[1];
    const float* user_feat_table    = (const float*)d_in[2];
    const float* item_feat_table    = (const float*)d_in[3];
    const float* word_emb           = (const float*)d_in[4];
    const float* user_numeric       = (const float*)d_in[5];
    const float* item_numeric       = (const float*)d_in[6];
    const float* user_word_embedding= (const float*)d_in[7];
    const float* item_word_embedding= (const float*)d_in[8];
    const float* item_sentence_emb  = (const float*)d_in[9];
    const float* user_num_W         = (const float*)d_in[10];
    const float* user_num_b         = (const float*)d_in[11];
    const float* item_num_W         = (const float*)d_in[12];
    const float* item_num_b         = (const float*)d_in[13];
    const float* user_proj_W        = (const float*)d_in[14];
    const float* user_proj_b        = (const float*)d_in[15];
    const float* item_proj_W        = (const float*)d_in[16];
    const float* item_proj_b        = (const float*)d_in[17];
    const float* w_W                = (const float*)d_in[18];
    const float* w_b                = (const float*)d_in[19];
    const float* v_W                = (const float*)d_in[20];
    const float* v_b                = (const float*)d_in[21];
    const int*   user_feat_idx      = (const int*)d_in[22];
    const int*   item_feat_idx      = (const int*)d_in[23];
    const int*   user_text_idx      = (const int*)d_in[24];
    const int*   item_text_idx      = (const int*)d_in[25];
    const int*   neighbors          = (const int*)d_in[26];

    // ws layout (bf16): x0 [NTOT][64], x1 [NTOT][64]  (fits exactly in SZ*4 bytes)
    unsigned short* x0 = (unsigned short*)d_ws;
    unsigned short* x1 = x0 + (size_t)NTOT * 64;

    // scratch in d_out tail: weights + bf16 gather tables (consumed before the
    // final layer overwrites d_out; init/L0 never write d_out)
    const size_t tail_elems = (size_t)64 * (KUP + KIP + 64 + 128)   // WTs
                            + 30000 * 32 + 5000 * 64 + 10000 * 64;  // tables
    char* tail = (char*)d_out + (size_t)out_size * 4 - tail_elems * 2;
    unsigned short* WTu  = (unsigned short*)tail;
    unsigned short* WTi  = WTu + 64 * KUP;
    unsigned short* VT0  = WTi + 64 * KIP;
    unsigned short* W20  = VT0 + 64 * 64;
    unsigned short* we16 = W20 + 64 * 128;
    unsigned short* ftu16= we16 + 30000 * 32;
    unsigned short* fti16= ftu16 + 5000 * 64;
    // layer-1 weights re-prepped into dead x0 region after L0
    unsigned short* VT1 = (unsigned short*)d_ws;
    unsigned short* W21 = VT1 + 64 * 64;

    prep_wt<<<dim3((KUP + 255) / 256, 64), 256, 0, stream>>>(user_proj_W, WTu, KU, KUP);
    prep_wt<<<dim3((KIP + 255) / 256, 64), 256, 0, stream>>>(item_proj_W, WTi, KI, KIP);
    prep_wt<<<dim3(1, 64), 256, 0, stream>>>(v_W, VT0, 64, 64);
    prep_wt<<<dim3(1, 64), 256, 0, stream>>>(w_W, W20, 128, 128);
    prep_cvt<<<(30000 * 32 + 255) / 256, 256, 0, stream>>>(word_emb, we16, 30000 * 32);
    prep_cvt<<<(5000 * 64 + 255) / 256, 256, 0, stream>>>(user_feat_table, ftu16, 5000 * 64);
    prep_cvt<<<(10000 * 64 + 255) / 256, 256, 0, stream>>>(item_feat_table, fti16, 10000 * 64);

    node_init_kernel<<<(NU + 63) / 64, 256, 0, stream>>>(
        user_id_emb, ftu16, we16, user_numeric,
        user_word_embedding, nullptr, user_feat_idx, user_text_idx,
        WTu, user_proj_b, user_num_W, user_num_b, x0, NU, KU, KUP, 0);
    node_init_kernel<<<(NI + 63) / 64, 256, 0, stream>>>(
        item_id_emb, fti16, we16, item_numeric,
        item_word_embedding, item_sentence_emb, item_feat_idx, item_text_idx,
        WTi, item_proj_b, item_num_W, item_num_b, x0, NI, KI, KIP, NU);

    // layer 0: x0 -> x1 (relu, bf16)
    gnn_layer_kernel<<<NTOT / 64, 256, 0, stream>>>(
        x0, neighbors, VT0, W20, v_b, w_b, x1, 0);

    // re-prep layer-1 weights into dead x0 region
    prep_wt<<<dim3(1, 64), 256, 0, stream>>>(v_W + 64 * 64, VT1, 64, 64);
    prep_wt<<<dim3(1, 64), 256, 0, stream>>>(w_W + 128 * 64, W21, 128, 128);

    // layer 1 + fused normalize: x1 -> d_out (fp32)
    gnn_layer_kernel<<<NTOT / 64, 256, 0, stream>>>(
        x1, neighbors, VT1, W21, v_b + 64, w_b + 64, d_out, 1);
}

// Round 7
// 691.068 us; speedup vs baseline: 1.0868x; 1.0746x over previous
//
#include <hip/hip_runtime.h>

typedef __attribute__((ext_vector_type(8))) short bf16x8;
typedef __attribute__((ext_vector_type(4))) float f32x4;
typedef __attribute__((ext_vector_type(4))) float f4v;

#define NU 150000
#define NI 50000
#define NTOT 200000
#define KU 524
#define KUP 576
#define KI 1292
#define KIP 1344

__device__ __forceinline__ f4v ld4(const float* p) { return *(const f4v*)p; }

__device__ __forceinline__ unsigned short bf16r(float x) {
    unsigned u = __float_as_uint(x);
    u += 0x7fff + ((u >> 16) & 1);
    return (unsigned short)(u >> 16);
}
__device__ __forceinline__ unsigned pk2(float lo, float hi) {
    unsigned a = __float_as_uint(lo), b = __float_as_uint(hi);
    a += 0x7fff + ((a >> 16) & 1);
    b += 0x7fff + ((b >> 16) & 1);
    return (a >> 16) | (b & 0xffff0000u);
}
__device__ __forceinline__ float bflo(unsigned s) { return __uint_as_float(s << 16); }
__device__ __forceinline__ float bfhi(unsigned s) { return __uint_as_float(s & 0xffff0000u); }

// accumulate 16 bf16 (32B) from p into s[0..15]
__device__ __forceinline__ void add16(float* s, const unsigned short* p) {
    const uint4 q0 = *(const uint4*)p;
    const uint4 q1 = *(const uint4*)(p + 8);
    s[0] += bflo(q0.x); s[1] += bfhi(q0.x); s[2] += bflo(q0.y); s[3] += bfhi(q0.y);
    s[4] += bflo(q0.z); s[5] += bfhi(q0.z); s[6] += bflo(q0.w); s[7] += bfhi(q0.w);
    s[8] += bflo(q1.x); s[9] += bfhi(q1.x); s[10] += bflo(q1.y); s[11] += bfhi(q1.y);
    s[12] += bflo(q1.z); s[13] += bfhi(q1.z); s[14] += bflo(q1.w); s[15] += bfhi(q1.w);
}

// W [K][64] fp32 -> WT [64][Kpad] bf16 (zero-padded K)
__global__ void prep_wt(const float* __restrict__ src, unsigned short* __restrict__ dst,
                        int K, int Kpad) {
    const int c = blockIdx.y;
    const int k = blockIdx.x * 256 + threadIdx.x;
    if (k >= Kpad) return;
    dst[(size_t)c * Kpad + k] = (k < K) ? bf16r(src[(size_t)k * 64 + c]) : (unsigned short)0;
}

// flat fp32 -> bf16 convert
__global__ void prep_cvt(const float* __restrict__ src, unsigned short* __restrict__ dst, int n) {
    const int i = blockIdx.x * 256 + threadIdx.x;
    if (i < n) dst[i] = bf16r(src[i]);
}

// ---------------------------------------------------------------------------
// Fused node-feature build + projection via MFMA. 64 rows/block, 4 waves.
// NO nt hints (R5 lesson: nt bundle regressed). Gathers read bf16 tables.
// Epilogue: LDS-transpose so output stores are full-line coalesced uint4.
// ---------------------------------------------------------------------------
__global__ __launch_bounds__(256, 6) void node_init_kernel(
    const float* __restrict__ id_emb, const unsigned short* __restrict__ ftab16,
    const unsigned short* __restrict__ wemb16, const float* __restrict__ numeric,
    const float* __restrict__ wordvec, const float* __restrict__ sentence,
    const int* __restrict__ feat_idx, const int* __restrict__ text_idx,
    const unsigned short* __restrict__ WT, const float* __restrict__ projb,
    const float* __restrict__ numW, const float* __restrict__ numb,
    unsigned short* __restrict__ x_out, int n, int Ktot, int Kpad, int row_off)
{
    __shared__ __align__(16) unsigned short aS[64][72];
    __shared__ unsigned short fiS[64][5];
    __shared__ unsigned short tiS[64][24];
    __shared__ float nmrS[64][10];

    const int t = threadIdx.x;
    const int row0 = blockIdx.x * 64;

    for (int e = t; e < 64 * 5; e += 256) {
        const int r = e / 5, j = e - r * 5, row = row0 + r;
        fiS[r][j] = (row < n) ? (unsigned short)feat_idx[row * 5 + j] : (unsigned short)0;
    }
    for (int e = t; e < 64 * 24; e += 256) {
        const int r = e / 24, j = e - r * 24, row = row0 + r;
        tiS[r][j] = (row < n) ? (unsigned short)text_idx[row * 24 + j] : (unsigned short)0;
    }
    for (int e = t; e < 64 * 10; e += 256) {
        const int r = e / 10, j = e - r * 10, row = row0 + r;
        nmrS[r][j] = (row < n) ? numeric[(size_t)row * 10 + j] : 0.f;
    }
    __syncthreads();

    const int sr  = t >> 2;            // staging row
    const int scq = (t & 3) * 16;      // staging col chunk (floats)
    const int srow = row0 + sr;
    const bool svalid = srow < n;

    const int lane = t & 63;
    const int w16 = (t >> 6) * 16;
    const int l15 = lane & 15;
    const int hi8 = (lane >> 4) * 8;
    const int g4  = (lane >> 4) * 4;

    f32x4 acc[4];
    #pragma unroll
    for (int ct = 0; ct < 4; ++ct) acc[ct] = (f32x4){0.f, 0.f, 0.f, 0.f};

    f4v vals[4];
    auto load_tile = [&](int kt) {
        const int k16 = kt * 64 + scq;
        if (svalid && k16 >= 64 && k16 < 224) {
            // whole 16-col chunk inside one gather segment (boundaries are x16)
            float s[16];
            #pragma unroll
            for (int i = 0; i < 16; ++i) s[i] = 0.f;
            if (k16 < 128) {
                const int c = k16 - 64;
                #pragma unroll
                for (int m = 0; m < 5; ++m)
                    add16(s, ftab16 + (size_t)fiS[sr][m] * 64 + c);
                #pragma unroll
                for (int i = 0; i < 16; ++i) s[i] *= 0.2f;
            } else {
                const int k2 = k16 - 128;
                const int f = k2 >> 5, c = k2 & 31;
                #pragma unroll
                for (int m = 0; m < 8; ++m)
                    add16(s, wemb16 + (size_t)tiS[sr][f * 8 + m] * 32 + c);
                #pragma unroll
                for (int i = 0; i < 16; ++i) s[i] *= 0.125f;
            }
            #pragma unroll
            for (int j = 0; j < 4; ++j)
                vals[j] = (f4v){s[4 * j], s[4 * j + 1], s[4 * j + 2], s[4 * j + 3]};
        } else {
            #pragma unroll
            for (int j = 0; j < 4; ++j) {
                const int k4 = k16 + j * 4;
                f4v v = (f4v){0.f, 0.f, 0.f, 0.f};
                if (svalid && k4 < Ktot) {
                    if (k4 >= 524)      v = ld4(sentence + (size_t)srow * 768 + (k4 - 524));
                    else if (k4 >= 224) v = ld4(wordvec + (size_t)srow * 300 + (k4 - 224));
                    else                v = ld4(id_emb + (size_t)srow * 64 + k4);
                }
                vals[j] = v;
            }
        }
    };

    const int NT = Kpad / 64;
    load_tile(0);
    for (int kt = 0; kt < NT; ++kt) {
        __syncthreads();   // previous tile's MFMA readers done
        #pragma unroll
        for (int j = 0; j < 2; ++j) {
            const f4v a0 = vals[2 * j], a1 = vals[2 * j + 1];
            uint4 pk;
            pk.x = pk2(a0.x, a0.y); pk.y = pk2(a0.z, a0.w);
            pk.z = pk2(a1.x, a1.y); pk.w = pk2(a1.z, a1.w);
            *(uint4*)&aS[sr][scq + j * 8] = pk;
        }
        __syncthreads();   // tile visible
        if (kt + 1 < NT) load_tile(kt + 1);   // prefetch, hidden under MFMA
        #pragma unroll
        for (int ks = 0; ks < 2; ++ks) {
            const bf16x8 af = *(const bf16x8*)&aS[w16 + l15][ks * 32 + hi8];
            #pragma unroll
            for (int ct = 0; ct < 4; ++ct) {
                const bf16x8 bfr = *(const bf16x8*)&WT[(size_t)(ct * 16 + l15) * Kpad
                                                      + kt * 64 + ks * 32 + hi8];
                acc[ct] = __builtin_amdgcn_mfma_f32_16x16x32_bf16(af, bfr, acc[ct], 0, 0, 0);
            }
        }
    }

    // epilogue: proj bias + numeric side-GEMM + num bias -> LDS transpose ->
    // coalesced full-line stores
    __syncthreads();   // done with aS as A-tile
    #pragma unroll
    for (int ct = 0; ct < 4; ++ct) {
        const int c = ct * 16 + l15;
        const float pb = projb[c] + numb[c];
        float wn[10];
        #pragma unroll
        for (int m = 0; m < 10; ++m) wn[m] = numW[m * 64 + c];
        #pragma unroll
        for (int j = 0; j < 4; ++j) {
            const int r = w16 + g4 + j;
            float s = acc[ct][j] + pb;
            #pragma unroll
            for (int m = 0; m < 10; ++m) s += nmrS[r][m] * wn[m];
            aS[r][c] = bf16r(s);
        }
    }
    __syncthreads();
    {
        const int r = t >> 2, cc = (t & 3) * 16;
        const int orow = row0 + r;
        if (orow < n) {
            const uint4 v0 = *(const uint4*)&aS[r][cc];
            const uint4 v1 = *(const uint4*)&aS[r][cc + 8];
            unsigned short* dst = x_out + (size_t)(row_off + orow) * 64 + cc;
            *(uint4*)dst = v0;
            *(uint4*)(dst + 8) = v1;
        }
    }
}

// ---------------------------------------------------------------------------
// GNN layer via MFMA. 64 rows/block. nm(bf16 LDS) -> agg MFMA -> ag(LDS) ->
// out = [x | ag] @ W2. bf16 output path uses LDS-transpose coalesced stores.
// ---------------------------------------------------------------------------
__global__ __launch_bounds__(256, 6) void gnn_layer_kernel(
    const unsigned short* __restrict__ x, const int* __restrict__ nbr,
    const unsigned short* __restrict__ VT, const unsigned short* __restrict__ W2T,
    const float* __restrict__ vb, const float* __restrict__ wb,
    void* __restrict__ outp, int finalize)
{
    __shared__ __align__(16) unsigned short mS[64][72];
    __shared__ int nbs[64][8];
    const int t = threadIdx.x;
    const int row0 = blockIdx.x * 64;

    for (int e = t; e < 512; e += 256) nbs[e >> 3][e & 7] = nbr[row0 * 8 + e];
    __syncthreads();

    {   // neighbor mean -> mS (bf16)
        const int r = t >> 2, c16 = (t & 3) * 16;
        float s[16];
        #pragma unroll
        for (int i = 0; i < 16; ++i) s[i] = 0.f;
        #pragma unroll
        for (int m = 0; m < 8; ++m)
            add16(s, x + (size_t)nbs[r][m] * 64 + c16);
        uint4 o0, o1;
        o0.x = pk2(s[0] * 0.125f, s[1] * 0.125f);
        o0.y = pk2(s[2] * 0.125f, s[3] * 0.125f);
        o0.z = pk2(s[4] * 0.125f, s[5] * 0.125f);
        o0.w = pk2(s[6] * 0.125f, s[7] * 0.125f);
        o1.x = pk2(s[8] * 0.125f, s[9] * 0.125f);
        o1.y = pk2(s[10] * 0.125f, s[11] * 0.125f);
        o1.z = pk2(s[12] * 0.125f, s[13] * 0.125f);
        o1.w = pk2(s[14] * 0.125f, s[15] * 0.125f);
        *(uint4*)&mS[r][c16] = o0;
        *(uint4*)&mS[r][c16 + 8] = o1;
    }
    __syncthreads();

    const int lane = t & 63;
    const int w16 = (t >> 6) * 16;
    const int l15 = lane & 15;
    const int hi8 = (lane >> 4) * 8;
    const int g4  = (lane >> 4) * 4;

    // agg = nm @ vW
    f32x4 ag[4];
    #pragma unroll
    for (int ct = 0; ct < 4; ++ct) ag[ct] = (f32x4){0.f, 0.f, 0.f, 0.f};
    #pragma unroll
    for (int ks = 0; ks < 2; ++ks) {
        const bf16x8 af = *(const bf16x8*)&mS[w16 + l15][ks * 32 + hi8];
        #pragma unroll
        for (int ct = 0; ct < 4; ++ct) {
            const bf16x8 bfr = *(const bf16x8*)&VT[(ct * 16 + l15) * 64 + ks * 32 + hi8];
            ag[ct] = __builtin_amdgcn_mfma_f32_16x16x32_bf16(af, bfr, ag[ct], 0, 0, 0);
        }
    }
    __syncthreads();   // nm readers done
    #pragma unroll
    for (int ct = 0; ct < 4; ++ct) {
        const int c = ct * 16 + l15;
        const float b = vb[c];
        #pragma unroll
        for (int j = 0; j < 4; ++j)
            mS[w16 + g4 + j][c] = bf16r(ag[ct][j] + b);
    }
    __syncthreads();

    // out = [x | ag] @ wW
    f32x4 acc[4];
    #pragma unroll
    for (int ct = 0; ct < 4; ++ct) acc[ct] = (f32x4){0.f, 0.f, 0.f, 0.f};
    #pragma unroll
    for (int ks = 0; ks < 4; ++ks) {
        bf16x8 af;
        if (ks < 2) af = *(const bf16x8*)&x[(size_t)(row0 + w16 + l15) * 64 + ks * 32 + hi8];
        else        af = *(const bf16x8*)&mS[w16 + l15][(ks - 2) * 32 + hi8];
        #pragma unroll
        for (int ct = 0; ct < 4; ++ct) {
            const bf16x8 bfr = *(const bf16x8*)&W2T[(ct * 16 + l15) * 128 + ks * 32 + hi8];
            acc[ct] = __builtin_amdgcn_mfma_f32_16x16x32_bf16(af, bfr, acc[ct], 0, 0, 0);
        }
    }

    if (!finalize) {
        // bf16 out: LDS transpose -> coalesced full-line stores
        __syncthreads();   // done with mS
        #pragma unroll
        for (int ct = 0; ct < 4; ++ct) {
            const int c = ct * 16 + l15;
            const float b = wb[c];
            #pragma unroll
            for (int j = 0; j < 4; ++j)
                mS[w16 + g4 + j][c] = bf16r(fmaxf(acc[ct][j] + b, 0.f));
        }
        __syncthreads();
        const int r = t >> 2, cc = (t & 3) * 16;
        const uint4 v0 = *(const uint4*)&mS[r][cc];
        const uint4 v1 = *(const uint4*)&mS[r][cc + 8];
        unsigned short* dst = (unsigned short*)outp + (size_t)(row0 + r) * 64 + cc;
        *(uint4*)dst = v0;
        *(uint4*)(dst + 8) = v1;
    } else {
        float* fo = (float*)outp;
        float vc[4][4], ss[4];
        #pragma unroll
        for (int j = 0; j < 4; ++j) ss[j] = 0.f;
        #pragma unroll
        for (int ct = 0; ct < 4; ++ct) {
            const float b = wb[ct * 16 + l15];
            #pragma unroll
            for (int j = 0; j < 4; ++j) {
                vc[ct][j] = acc[ct][j] + b;
                ss[j] += vc[ct][j] * vc[ct][j];
            }
        }
        #pragma unroll
        for (int m = 1; m < 16; m <<= 1) {
            #pragma unroll
            for (int j = 0; j < 4; ++j) ss[j] += __shfl_xor(ss[j], m, 64);
        }
        #pragma unroll
        for (int j = 0; j < 4; ++j) ss[j] = 1.f / fmaxf(sqrtf(ss[j]), 1e-12f);
        #pragma unroll
        for (int ct = 0; ct < 4; ++ct) {
            const int c = ct * 16 + l15;
            #pragma unroll
            for (int j = 0; j < 4; ++j)
                fo[(size_t)(row0 + w16 + g4 + j) * 64 + c] = vc[ct][j] * ss[j];
        }
    }
}

extern "C" void kernel_launch(void* const* d_in, const int* in_sizes, int n_in,
                              void* d_out, int out_size, void* d_ws, size_t ws_size,
                              hipStream_t stream) {
    const float* user_id_emb        = (const float*)d_in[0];
    const float* item_id_emb        = (const float*)d_in[1];
    const float* user_feat_table    = (const float*)d_in[2];
    const float* item_feat_table    = (const float*)d_in[3];
    const float* word_emb           = (const float*)d_in[4];
    const float* user_numeric       = (const float*)d_in[5];
    const float* item_numeric       = (const float*)d_in[6];
    const float* user_word_embedding= (const float*)d_in[7];
    const float* item_word_embedding= (const float*)d_in[8];
    const float* item_sentence_emb  = (const float*)d_in[9];
    const float* user_num_W         = (const float*)d_in[10];
    const float* user_num_b         = (const float*)d_in[11];
    const float* item_num_W         = (const float*)d_in[12];
    const float* item_num_b         = (const float*)d_in[13];
    const float* user_proj_W        = (const float*)d_in[14];
    const float* user_proj_b        = (const float*)d_in[15];
    const float* item_proj_W        = (const float*)d_in[16];
    const float* item_proj_b        = (const float*)d_in[17];
    const float* w_W                = (const float*)d_in[18];
    const float* w_b                = (const float*)d_in[19];
    const float* v_W                = (const float*)d_in[20];
    const float* v_b                = (const float*)d_in[21];
    const int*   user_feat_idx      = (const int*)d_in[22];
    const int*   item_feat_idx      = (const int*)d_in[23];
    const int*   user_text_idx      = (const int*)d_in[24];
    const int*   item_text_idx      = (const int*)d_in[25];
    const int*   neighbors          = (const int*)d_in[26];

    // ws layout (bf16): x0 [NTOT][64], x1 [NTOT][64]  (fits exactly in SZ*4 bytes)
    unsigned short* x0 = (unsigned short*)d_ws;
    unsigned short* x1 = x0 + (size_t)NTOT * 64;

    // scratch in d_out tail: weights + bf16 gather tables (consumed before the
    // final layer overwrites d_out; init/L0 never write d_out)
    const size_t tail_elems = (size_t)64 * (KUP + KIP + 64 + 128)   // WTs
                            + 30000 * 32 + 5000 * 64 + 10000 * 64;  // tables
    char* tail = (char*)d_out + (size_t)out_size * 4 - tail_elems * 2;
    unsigned short* WTu  = (unsigned short*)tail;
    unsigned short* WTi  = WTu + 64 * KUP;
    unsigned short* VT0  = WTi + 64 * KIP;
    unsigned short* W20  = VT0 + 64 * 64;
    unsigned short* we16 = W20 + 64 * 128;
    unsigned short* ftu16= we16 + 30000 * 32;
    unsigned short* fti16= ftu16 + 5000 * 64;
    // layer-1 weights re-prepped into dead x0 region after L0
    unsigned short* VT1 = (unsigned short*)d_ws;
    unsigned short* W21 = VT1 + 64 * 64;

    prep_wt<<<dim3((KUP + 255) / 256, 64), 256, 0, stream>>>(user_proj_W, WTu, KU, KUP);
    prep_wt<<<dim3((KIP + 255) / 256, 64), 256, 0, stream>>>(item_proj_W, WTi, KI, KIP);
    prep_wt<<<dim3(1, 64), 256, 0, stream>>>(v_W, VT0, 64, 64);
    prep_wt<<<dim3(1, 64), 256, 0, stream>>>(w_W, W20, 128, 128);
    prep_cvt<<<(30000 * 32 + 255) / 256, 256, 0, stream>>>(word_emb, we16, 30000 * 32);
    prep_cvt<<<(5000 * 64 + 255) / 256, 256, 0, stream>>>(user_feat_table, ftu16, 5000 * 64);
    prep_cvt<<<(10000 * 64 + 255) / 256, 256, 0, stream>>>(item_feat_table, fti16, 10000 * 64);

    node_init_kernel<<<(NU + 63) / 64, 256, 0, stream>>>(
        user_id_emb, ftu16, we16, user_numeric,
        user_word_embedding, nullptr, user_feat_idx, user_text_idx,
        WTu, user_proj_b, user_num_W, user_num_b, x0, NU, KU, KUP, 0);
    node_init_kernel<<<(NI + 63) / 64, 256, 0, stream>>>(
        item_id_emb, fti16, we16, item_numeric,
        item_word_embedding, item_sentence_emb, item_feat_idx, item_text_idx,
        WTi, item_proj_b, item_num_W, item_num_b, x0, NI, KI, KIP, NU);

    // layer 0: x0 -> x1 (relu, bf16)
    gnn_layer_kernel<<<NTOT / 64, 256, 0, stream>>>(
        x0, neighbors, VT0, W20, v_b, w_b, x1, 0);

    // re-prep layer-1 weights into dead x0 region
    prep_wt<<<dim3(1, 64), 256, 0, stream>>>(v_W + 64 * 64, VT1, 64, 64);
    prep_wt<<<dim3(1, 64), 256, 0, stream>>>(w_W + 128 * 64, W21, 128, 128);

    // layer 1 + fused normalize: x1 -> d_out (fp32)
    gnn_layer_kernel<<<NTOT / 64, 256, 0, stream>>>(
        x1, neighbors, VT1, W21, v_b + 64, w_b + 64, d_out, 1);
}

// Round 8
// 652.862 us; speedup vs baseline: 1.1504x; 1.0585x over previous
//
#include <hip/hip_runtime.h>

typedef __attribute__((ext_vector_type(8))) short bf16x8;
typedef __attribute__((ext_vector_type(4))) float f32x4;
typedef __attribute__((ext_vector_type(4))) float f4v;

#define NU 150000
#define NI 50000
#define NTOT 200000
#define KU 524
#define KUP 576
#define KI 1292
#define KIP 1344

__device__ __forceinline__ f4v ld4(const float* p) { return *(const f4v*)p; }

__device__ __forceinline__ unsigned short bf16r(float x) {
    unsigned u = __float_as_uint(x);
    u += 0x7fff + ((u >> 16) & 1);
    return (unsigned short)(u >> 16);
}
__device__ __forceinline__ unsigned pk2(float lo, float hi) {
    unsigned a = __float_as_uint(lo), b = __float_as_uint(hi);
    a += 0x7fff + ((a >> 16) & 1);
    b += 0x7fff + ((b >> 16) & 1);
    return (a >> 16) | (b & 0xffff0000u);
}
__device__ __forceinline__ float bfu(unsigned short u) {
    return __uint_as_float((unsigned)u << 16);
}

// W [K][64] fp32 -> WT [64][Kpad] bf16 (zero-padded K)
__global__ void prep_wt(const float* __restrict__ src, unsigned short* __restrict__ dst,
                        int K, int Kpad) {
    const int c = blockIdx.y;
    const int k = blockIdx.x * 256 + threadIdx.x;
    if (k >= Kpad) return;
    dst[(size_t)c * Kpad + k] = (k < K) ? bf16r(src[(size_t)k * 64 + c]) : (unsigned short)0;
}

// ---------------------------------------------------------------------------
// Text-mean pre-pass: one thread per (node, field). mean of 8 word_emb rows
// (32 fp32 each) -> stage[node][field*32..] bf16. Isolated kernel => word_emb
// (3.84MB) + text_idx are the only working set => L2-resident gathers.
// ---------------------------------------------------------------------------
__global__ __launch_bounds__(256, 8) void txt_mean_kernel(
    const float* __restrict__ word_emb,
    const int* __restrict__ u_text_idx, const int* __restrict__ i_text_idx,
    unsigned short* __restrict__ stage)
{
    const int gid = blockIdx.x * 256 + threadIdx.x;   // node*3 + field
    if (gid >= NTOT * 3) return;
    const int node = gid / 3, f = gid - node * 3;
    const int* tip = (node < NU) ? (u_text_idx + ((size_t)node * 3 + f) * 8)
                                 : (i_text_idx + ((size_t)(node - NU) * 3 + f) * 8);
    int ti[8];
    {
        const int4 a = *(const int4*)tip;
        const int4 b = *(const int4*)(tip + 4);
        ti[0] = a.x; ti[1] = a.y; ti[2] = a.z; ti[3] = a.w;
        ti[4] = b.x; ti[5] = b.y; ti[6] = b.z; ti[7] = b.w;
    }
    float s[32];
    #pragma unroll
    for (int i = 0; i < 32; ++i) s[i] = 0.f;
    #pragma unroll
    for (int m = 0; m < 8; ++m) {
        const float* p = word_emb + (size_t)ti[m] * 32;
        #pragma unroll
        for (int q = 0; q < 8; ++q) {
            const f4v g = ld4(p + q * 4);
            s[q * 4 + 0] += g.x; s[q * 4 + 1] += g.y;
            s[q * 4 + 2] += g.z; s[q * 4 + 3] += g.w;
        }
    }
    unsigned short* dst = stage + (size_t)node * 96 + f * 32;
    #pragma unroll
    for (int q = 0; q < 4; ++q) {
        uint4 o;
        o.x = pk2(s[q * 8 + 0] * 0.125f, s[q * 8 + 1] * 0.125f);
        o.y = pk2(s[q * 8 + 2] * 0.125f, s[q * 8 + 3] * 0.125f);
        o.z = pk2(s[q * 8 + 4] * 0.125f, s[q * 8 + 5] * 0.125f);
        o.w = pk2(s[q * 8 + 6] * 0.125f, s[q * 8 + 7] * 0.125f);
        *(uint4*)(dst + q * 8) = o;
    }
}

// ---------------------------------------------------------------------------
// Fused node-feature build + projection via MFMA. 64 rows/block, 4 waves.
// Text cols come from the txt_mean staging buffer (pure stream); feat gathers
// read the fp32 d_in table (R3-proven path). No nt hints anywhere.
// ---------------------------------------------------------------------------
__global__ __launch_bounds__(256, 6) void node_init_kernel(
    const float* __restrict__ id_emb, const float* __restrict__ feat_table,
    const unsigned short* __restrict__ txt_stage, const float* __restrict__ numeric,
    const float* __restrict__ wordvec, const float* __restrict__ sentence,
    const int* __restrict__ feat_idx,
    const unsigned short* __restrict__ WT, const float* __restrict__ projb,
    const float* __restrict__ numW, const float* __restrict__ numb,
    unsigned short* __restrict__ x_out, int n, int Ktot, int Kpad, int row_off)
{
    __shared__ __align__(16) unsigned short aS[64][72];
    __shared__ unsigned short fiS[64][5];
    __shared__ float nmrS[64][10];

    const int t = threadIdx.x;
    const int row0 = blockIdx.x * 64;

    for (int e = t; e < 64 * 5; e += 256) {
        const int r = e / 5, j = e - r * 5, row = row0 + r;
        fiS[r][j] = (row < n) ? (unsigned short)feat_idx[row * 5 + j] : (unsigned short)0;
    }
    for (int e = t; e < 64 * 10; e += 256) {
        const int r = e / 10, j = e - r * 10, row = row0 + r;
        nmrS[r][j] = (row < n) ? numeric[(size_t)row * 10 + j] : 0.f;
    }
    __syncthreads();

    const int sr  = t >> 2;            // staging row
    const int scq = (t & 3) * 16;      // staging col chunk (floats)
    const int srow = row0 + sr;
    const bool svalid = srow < n;
    const size_t gnode = (size_t)(row_off + srow);

    const int lane = t & 63;
    const int w16 = (t >> 6) * 16;
    const int l15 = lane & 15;
    const int hi8 = (lane >> 4) * 8;
    const int g4  = (lane >> 4) * 4;

    f32x4 acc[4];
    #pragma unroll
    for (int ct = 0; ct < 4; ++ct) acc[ct] = (f32x4){0.f, 0.f, 0.f, 0.f};

    f4v vals[4];
    auto load_tile = [&](int kt) {
        #pragma unroll
        for (int j = 0; j < 4; ++j) {
            const int k4 = kt * 64 + scq + j * 4;
            f4v v = (f4v){0.f, 0.f, 0.f, 0.f};
            if (svalid && k4 < Ktot) {
                if (k4 >= 524) {
                    v = ld4(sentence + (size_t)srow * 768 + (k4 - 524));
                } else if (k4 >= 224) {
                    v = ld4(wordvec + (size_t)srow * 300 + (k4 - 224));
                } else if (k4 >= 128) {
                    const ushort4 q = *(const ushort4*)(txt_stage + gnode * 96 + (k4 - 128));
                    v.x = bfu(q.x); v.y = bfu(q.y); v.z = bfu(q.z); v.w = bfu(q.w);
                } else if (k4 >= 64) {
                    const int c = k4 - 64;
                    f4v s = (f4v){0.f, 0.f, 0.f, 0.f};
                    #pragma unroll
                    for (int m = 0; m < 5; ++m) {
                        const f4v g = ld4(feat_table + (size_t)fiS[sr][m] * 64 + c);
                        s.x += g.x; s.y += g.y; s.z += g.z; s.w += g.w;
                    }
                    v.x = s.x * 0.2f; v.y = s.y * 0.2f;
                    v.z = s.z * 0.2f; v.w = s.w * 0.2f;
                } else {
                    v = ld4(id_emb + (size_t)srow * 64 + k4);
                }
            }
            vals[j] = v;
        }
    };

    const int NT = Kpad / 64;
    load_tile(0);
    for (int kt = 0; kt < NT; ++kt) {
        __syncthreads();   // previous tile's MFMA readers done
        #pragma unroll
        for (int j = 0; j < 2; ++j) {
            const f4v a0 = vals[2 * j], a1 = vals[2 * j + 1];
            uint4 pk;
            pk.x = pk2(a0.x, a0.y); pk.y = pk2(a0.z, a0.w);
            pk.z = pk2(a1.x, a1.y); pk.w = pk2(a1.z, a1.w);
            *(uint4*)&aS[sr][scq + j * 8] = pk;
        }
        __syncthreads();   // tile visible
        if (kt + 1 < NT) load_tile(kt + 1);   // prefetch, hidden under MFMA
        #pragma unroll
        for (int ks = 0; ks < 2; ++ks) {
            const bf16x8 af = *(const bf16x8*)&aS[w16 + l15][ks * 32 + hi8];
            #pragma unroll
            for (int ct = 0; ct < 4; ++ct) {
                const bf16x8 bfr = *(const bf16x8*)&WT[(size_t)(ct * 16 + l15) * Kpad
                                                      + kt * 64 + ks * 32 + hi8];
                acc[ct] = __builtin_amdgcn_mfma_f32_16x16x32_bf16(af, bfr, acc[ct], 0, 0, 0);
            }
        }
    }

    // epilogue: proj bias + numeric side-GEMM + num bias, write bf16 (cached)
    #pragma unroll
    for (int ct = 0; ct < 4; ++ct) {
        const int c = ct * 16 + l15;
        const float pb = projb[c] + numb[c];
        float wn[10];
        #pragma unroll
        for (int m = 0; m < 10; ++m) wn[m] = numW[m * 64 + c];
        #pragma unroll
        for (int j = 0; j < 4; ++j) {
            const int r = w16 + g4 + j;
            const int row = row0 + r;
            if (row < n) {
                float s = acc[ct][j] + pb;
                #pragma unroll
                for (int m = 0; m < 10; ++m) s += nmrS[r][m] * wn[m];
                x_out[(size_t)(row_off + row) * 64 + c] = bf16r(s);
            }
        }
    }
}

// ---------------------------------------------------------------------------
// GNN layer via MFMA. 64 rows/block. (unchanged from the 591us R3 config)
// ---------------------------------------------------------------------------
__global__ __launch_bounds__(256, 6) void gnn_layer_kernel(
    const unsigned short* __restrict__ x, const int* __restrict__ nbr,
    const unsigned short* __restrict__ VT, const unsigned short* __restrict__ W2T,
    const float* __restrict__ vb, const float* __restrict__ wb,
    void* __restrict__ outp, int finalize)
{
    __shared__ __align__(16) unsigned short mS[64][72];
    __shared__ int nbs[64][8];
    const int t = threadIdx.x;
    const int row0 = blockIdx.x * 64;

    for (int e = t; e < 512; e += 256) nbs[e >> 3][e & 7] = nbr[row0 * 8 + e];
    __syncthreads();

    {   // neighbor mean -> mS (bf16)
        const int r = t >> 2, c16 = (t & 3) * 16;
        float s[16];
        #pragma unroll
        for (int i = 0; i < 16; ++i) s[i] = 0.f;
        #pragma unroll
        for (int m = 0; m < 8; ++m) {
            const unsigned short* p = x + (size_t)nbs[r][m] * 64 + c16;
            const uint4 q0 = *(const uint4*)p;
            const uint4 q1 = *(const uint4*)(p + 8);
            s[0] += bfu(q0.x & 0xffff); s[1] += bfu(q0.x >> 16);
            s[2] += bfu(q0.y & 0xffff); s[3] += bfu(q0.y >> 16);
            s[4] += bfu(q0.z & 0xffff); s[5] += bfu(q0.z >> 16);
            s[6] += bfu(q0.w & 0xffff); s[7] += bfu(q0.w >> 16);
            s[8] += bfu(q1.x & 0xffff); s[9] += bfu(q1.x >> 16);
            s[10] += bfu(q1.y & 0xffff); s[11] += bfu(q1.y >> 16);
            s[12] += bfu(q1.z & 0xffff); s[13] += bfu(q1.z >> 16);
            s[14] += bfu(q1.w & 0xffff); s[15] += bfu(q1.w >> 16);
        }
        uint4 o0, o1;
        o0.x = pk2(s[0] * 0.125f, s[1] * 0.125f);
        o0.y = pk2(s[2] * 0.125f, s[3] * 0.125f);
        o0.z = pk2(s[4] * 0.125f, s[5] * 0.125f);
        o0.w = pk2(s[6] * 0.125f, s[7] * 0.125f);
        o1.x = pk2(s[8] * 0.125f, s[9] * 0.125f);
        o1.y = pk2(s[10] * 0.125f, s[11] * 0.125f);
        o1.z = pk2(s[12] * 0.125f, s[13] * 0.125f);
        o1.w = pk2(s[14] * 0.125f, s[15] * 0.125f);
        *(uint4*)&mS[r][c16] = o0;
        *(uint4*)&mS[r][c16 + 8] = o1;
    }
    __syncthreads();

    const int lane = t & 63;
    const int w16 = (t >> 6) * 16;
    const int l15 = lane & 15;
    const int hi8 = (lane >> 4) * 8;
    const int g4  = (lane >> 4) * 4;

    // agg = nm @ vW
    f32x4 ag[4];
    #pragma unroll
    for (int ct = 0; ct < 4; ++ct) ag[ct] = (f32x4){0.f, 0.f, 0.f, 0.f};
    #pragma unroll
    for (int ks = 0; ks < 2; ++ks) {
        const bf16x8 af = *(const bf16x8*)&mS[w16 + l15][ks * 32 + hi8];
        #pragma unroll
        for (int ct = 0; ct < 4; ++ct) {
            const bf16x8 bfr = *(const bf16x8*)&VT[(ct * 16 + l15) * 64 + ks * 32 + hi8];
            ag[ct] = __builtin_amdgcn_mfma_f32_16x16x32_bf16(af, bfr, ag[ct], 0, 0, 0);
        }
    }
    __syncthreads();   // nm readers done
    #pragma unroll
    for (int ct = 0; ct < 4; ++ct) {
        const int c = ct * 16 + l15;
        const float b = vb[c];
        #pragma unroll
        for (int j = 0; j < 4; ++j)
            mS[w16 + g4 + j][c] = bf16r(ag[ct][j] + b);
    }
    __syncthreads();

    // out = [x | ag] @ wW
    f32x4 acc[4];
    #pragma unroll
    for (int ct = 0; ct < 4; ++ct) acc[ct] = (f32x4){0.f, 0.f, 0.f, 0.f};
    #pragma unroll
    for (int ks = 0; ks < 4; ++ks) {
        bf16x8 af;
        if (ks < 2) af = *(const bf16x8*)&x[(size_t)(row0 + w16 + l15) * 64 + ks * 32 + hi8];
        else        af = *(const bf16x8*)&mS[w16 + l15][(ks - 2) * 32 + hi8];
        #pragma unroll
        for (int ct = 0; ct < 4; ++ct) {
            const bf16x8 bfr = *(const bf16x8*)&W2T[(ct * 16 + l15) * 128 + ks * 32 + hi8];
            acc[ct] = __builtin_amdgcn_mfma_f32_16x16x32_bf16(af, bfr, acc[ct], 0, 0, 0);
        }
    }

    if (!finalize) {
        unsigned short* xo = (unsigned short*)outp;
        #pragma unroll
        for (int ct = 0; ct < 4; ++ct) {
            const int c = ct * 16 + l15;
            const float b = wb[c];
            #pragma unroll
            for (int j = 0; j < 4; ++j)
                xo[(size_t)(row0 + w16 + g4 + j) * 64 + c] = bf16r(fmaxf(acc[ct][j] + b, 0.f));
        }
    } else {
        float* fo = (float*)outp;
        float vc[4][4], ss[4];
        #pragma unroll
        for (int j = 0; j < 4; ++j) ss[j] = 0.f;
        #pragma unroll
        for (int ct = 0; ct < 4; ++ct) {
            const float b = wb[ct * 16 + l15];
            #pragma unroll
            for (int j = 0; j < 4; ++j) {
                vc[ct][j] = acc[ct][j] + b;
                ss[j] += vc[ct][j] * vc[ct][j];
            }
        }
        #pragma unroll
        for (int m = 1; m < 16; m <<= 1) {
            #pragma unroll
            for (int j = 0; j < 4; ++j) ss[j] += __shfl_xor(ss[j], m, 64);
        }
        #pragma unroll
        for (int j = 0; j < 4; ++j) ss[j] = 1.f / fmaxf(sqrtf(ss[j]), 1e-12f);
        #pragma unroll
        for (int ct = 0; ct < 4; ++ct) {
            const int c = ct * 16 + l15;
            #pragma unroll
            for (int j = 0; j < 4; ++j)
                fo[(size_t)(row0 + w16 + g4 + j) * 64 + c] = vc[ct][j] * ss[j];
        }
    }
}

extern "C" void kernel_launch(void* const* d_in, const int* in_sizes, int n_in,
                              void* d_out, int out_size, void* d_ws, size_t ws_size,
                              hipStream_t stream) {
    const float* user_id_emb        = (const float*)d_in[0];
    const float* item_id_emb        = (const float*)d_in[1];
    const float* user_feat_table    = (const float*)d_in[2];
    const float* item_feat_table    = (const float*)d_in[3];
    const float* word_emb           = (const float*)d_in[4];
    const float* user_numeric       = (const float*)d_in[5];
    const float* item_numeric       = (const float*)d_in[6];
    const float* user_word_embedding= (const float*)d_in[7];
    const float* item_word_embedding= (const float*)d_in[8];
    const float* item_sentence_emb  = (const float*)d_in[9];
    const float* user_num_W         = (const float*)d_in[10];
    const float* user_num_b         = (const float*)d_in[11];
    const float* item_num_W         = (const float*)d_in[12];
    const float* item_num_b         = (const float*)d_in[13];
    const float* user_proj_W        = (const float*)d_in[14];
    const float* user_proj_b        = (const float*)d_in[15];
    const float* item_proj_W        = (const float*)d_in[16];
    const float* item_proj_b        = (const float*)d_in[17];
    const float* w_W                = (const float*)d_in[18];
    const float* w_b                = (const float*)d_in[19];
    const float* v_W                = (const float*)d_in[20];
    const float* v_b                = (const float*)d_in[21];
    const int*   user_feat_idx      = (const int*)d_in[22];
    const int*   item_feat_idx      = (const int*)d_in[23];
    const int*   user_text_idx      = (const int*)d_in[24];
    const int*   item_text_idx      = (const int*)d_in[25];
    const int*   neighbors          = (const int*)d_in[26];

    // ws layout (bf16): x0 [NTOT][64], x1 [NTOT][64]
    unsigned short* x0 = (unsigned short*)d_ws;
    unsigned short* x1 = x0 + (size_t)NTOT * 64;

    // d_out FRONT: text-mean staging [NTOT][96] bf16 (38.4 MB, consumed by
    // node_init before the final layer overwrites d_out)
    unsigned short* txt_stage = (unsigned short*)d_out;
    // d_out TAIL: bf16 weights (R3-proven placement, 270 KB)
    const size_t prep_bytes = 2ull * 64 * (KUP + KIP + 64 + 128);
    char* WTbase = (char*)d_out + (size_t)out_size * 4 - prep_bytes;
    unsigned short* WTu = (unsigned short*)WTbase;
    unsigned short* WTi = WTu + 64 * KUP;
    unsigned short* VT0 = WTi + 64 * KIP;
    unsigned short* W20 = VT0 + 64 * 64;
    // layer-1 weights re-prepped into dead x0 region after L0
    unsigned short* VT1 = (unsigned short*)d_ws;
    unsigned short* W21 = VT1 + 64 * 64;

    prep_wt<<<dim3((KUP + 255) / 256, 64), 256, 0, stream>>>(user_proj_W, WTu, KU, KUP);
    prep_wt<<<dim3((KIP + 255) / 256, 64), 256, 0, stream>>>(item_proj_W, WTi, KI, KIP);
    prep_wt<<<dim3(1, 64), 256, 0, stream>>>(v_W, VT0, 64, 64);
    prep_wt<<<dim3(1, 64), 256, 0, stream>>>(w_W, W20, 128, 128);

    // text-mean pre-pass (isolated gather kernel, word_emb stays L2-resident)
    txt_mean_kernel<<<(NTOT * 3 + 255) / 256, 256, 0, stream>>>(
        word_emb, user_text_idx, item_text_idx, txt_stage);

    node_init_kernel<<<(NU + 63) / 64, 256, 0, stream>>>(
        user_id_emb, user_feat_table, txt_stage, user_numeric,
        user_word_embedding, nullptr, user_feat_idx,
        WTu, user_proj_b, user_num_W, user_num_b, x0, NU, KU, KUP, 0);
    node_init_kernel<<<(NI + 63) / 64, 256, 0, stream>>>(
        item_id_emb, item_feat_table, txt_stage, item_numeric,
        item_word_embedding, item_sentence_emb, item_feat_idx,
        WTi, item_proj_b, item_num_W, item_num_b, x0, NI, KI, KIP, NU);

    // layer 0: x0 -> x1 (relu, bf16)
    gnn_layer_kernel<<<NTOT / 64, 256, 0, stream>>>(
        x0, neighbors, VT0, W20, v_b, w_b, x1, 0);

    // re-prep layer-1 weights into dead x0 region
    prep_wt<<<dim3(1, 64), 256, 0, stream>>>(v_W + 64 * 64, VT1, 64, 64);
    prep_wt<<<dim3(1, 64), 256, 0, stream>>>(w_W + 128 * 64, W21, 128, 128);

    // layer 1 + fused normalize: x1 -> d_out (fp32, overwrites staging+weights)
    gnn_layer_kernel<<<NTOT / 64, 256, 0, stream>>>(
        x1, neighbors, VT1, W21, v_b + 64, w_b + 64, d_out, 1);
}

// Round 9
// 503.331 us; speedup vs baseline: 1.4922x; 1.2971x over previous
//
#include <hip/hip_runtime.h>

typedef __attribute__((ext_vector_type(8))) short bf16x8;
typedef __attribute__((ext_vector_type(4))) float f32x4;
typedef __attribute__((ext_vector_type(4))) float f4v;

#define NU 150000
#define NI 50000
#define NTOT 200000
#define KU 524
#define KUP 576
#define KI 1292
#define KIP 1344

__device__ __forceinline__ f4v ld4(const float* p) { return *(const f4v*)p; }

__device__ __forceinline__ unsigned short bf16r(float x) {
    unsigned u = __float_as_uint(x);
    u += 0x7fff + ((u >> 16) & 1);
    return (unsigned short)(u >> 16);
}
__device__ __forceinline__ unsigned pk2(float lo, float hi) {
    unsigned a = __float_as_uint(lo), b = __float_as_uint(hi);
    a += 0x7fff + ((a >> 16) & 1);
    b += 0x7fff + ((b >> 16) & 1);
    return (a >> 16) | (b & 0xffff0000u);
}
__device__ __forceinline__ float bfu(unsigned short u) {
    return __uint_as_float((unsigned)u << 16);
}

// W [K][64] fp32 -> WT [64][Kpad] bf16 (zero-padded K)
__global__ void prep_wt(const float* __restrict__ src, unsigned short* __restrict__ dst,
                        int K, int Kpad) {
    const int c = blockIdx.y;
    const int k = blockIdx.x * 256 + threadIdx.x;
    if (k >= Kpad) return;
    dst[(size_t)c * Kpad + k] = (k < K) ? bf16r(src[(size_t)k * 64 + c]) : (unsigned short)0;
}

// ---------------------------------------------------------------------------
// Text-mean pre-pass, wave-per-node layout. lane=(col c, half h): one gather
// instruction covers 2 complete 128B word_emb rows (32 lanes each) => 2 line
// requests/instr instead of 64 (R7 lesson: request-rate-bound at 38.4M lines).
// 12 gathers/wave + shfl_xor(32) combine + LDS-staged contiguous stores.
// ---------------------------------------------------------------------------
__global__ __launch_bounds__(256, 8) void txt_mean_kernel(
    const float* __restrict__ word_emb,
    const int* __restrict__ u_text_idx, const int* __restrict__ i_text_idx,
    unsigned short* __restrict__ stage)
{
    __shared__ __align__(16) unsigned short st[4][96];   // contiguous 768B
    const int wid  = threadIdx.x >> 6;
    const int lane = threadIdx.x & 63;
    const int node = blockIdx.x * 4 + wid;               // grid exact: NTOT/4
    const int c = lane & 31, h = lane >> 5;
    const int* tip = (node < NU) ? (u_text_idx + (size_t)node * 24)
                                 : (i_text_idx + (size_t)(node - NU) * 24);
    float s[3];
    #pragma unroll
    for (int f = 0; f < 3; ++f) {
        float a = 0.f;
        #pragma unroll
        for (int rr = 0; rr < 4; ++rr) {
            const int idx = tip[f * 8 + rr * 2 + h];     // 32-lane broadcast load
            a += word_emb[(size_t)idx * 32 + c];         // half-wave = full row
        }
        s[f] = a;
    }
    #pragma unroll
    for (int f = 0; f < 3; ++f) s[f] += __shfl_xor(s[f], 32, 64);
    if (h == 0) {
        #pragma unroll
        for (int f = 0; f < 3; ++f) st[wid][f * 32 + c] = bf16r(s[f] * 0.125f);
    }
    __syncthreads();
    // block = 4 consecutive nodes = 768B contiguous: 48 threads x uint4
    if (threadIdx.x < 48) {
        const uint4 v = *(const uint4*)&st[0][threadIdx.x * 8];
        *(uint4*)(stage + (size_t)blockIdx.x * 384 + threadIdx.x * 8) = v;
    }
}

// ---------------------------------------------------------------------------
// Fused node-feature build + projection via MFMA. 64 rows/block, 4 waves.
// Text cols come from the txt_mean staging buffer (pure stream); feat gathers
// read the fp32 d_in table (R3-proven path). No nt hints anywhere.
// ---------------------------------------------------------------------------
__global__ __launch_bounds__(256, 6) void node_init_kernel(
    const float* __restrict__ id_emb, const float* __restrict__ feat_table,
    const unsigned short* __restrict__ txt_stage, const float* __restrict__ numeric,
    const float* __restrict__ wordvec, const float* __restrict__ sentence,
    const int* __restrict__ feat_idx,
    const unsigned short* __restrict__ WT, const float* __restrict__ projb,
    const float* __restrict__ numW, const float* __restrict__ numb,
    unsigned short* __restrict__ x_out, int n, int Ktot, int Kpad, int row_off)
{
    __shared__ __align__(16) unsigned short aS[64][72];
    __shared__ unsigned short fiS[64][5];
    __shared__ float nmrS[64][10];

    const int t = threadIdx.x;
    const int row0 = blockIdx.x * 64;

    for (int e = t; e < 64 * 5; e += 256) {
        const int r = e / 5, j = e - r * 5, row = row0 + r;
        fiS[r][j] = (row < n) ? (unsigned short)feat_idx[row * 5 + j] : (unsigned short)0;
    }
    for (int e = t; e < 64 * 10; e += 256) {
        const int r = e / 10, j = e - r * 10, row = row0 + r;
        nmrS[r][j] = (row < n) ? numeric[(size_t)row * 10 + j] : 0.f;
    }
    __syncthreads();

    const int sr  = t >> 2;            // staging row
    const int scq = (t & 3) * 16;      // staging col chunk (floats)
    const int srow = row0 + sr;
    const bool svalid = srow < n;
    const size_t gnode = (size_t)(row_off + srow);

    const int lane = t & 63;
    const int w16 = (t >> 6) * 16;
    const int l15 = lane & 15;
    const int hi8 = (lane >> 4) * 8;
    const int g4  = (lane >> 4) * 4;

    f32x4 acc[4];
    #pragma unroll
    for (int ct = 0; ct < 4; ++ct) acc[ct] = (f32x4){0.f, 0.f, 0.f, 0.f};

    f4v vals[4];
    auto load_tile = [&](int kt) {
        #pragma unroll
        for (int j = 0; j < 4; ++j) {
            const int k4 = kt * 64 + scq + j * 4;
            f4v v = (f4v){0.f, 0.f, 0.f, 0.f};
            if (svalid && k4 < Ktot) {
                if (k4 >= 524) {
                    v = ld4(sentence + (size_t)srow * 768 + (k4 - 524));
                } else if (k4 >= 224) {
                    v = ld4(wordvec + (size_t)srow * 300 + (k4 - 224));
                } else if (k4 >= 128) {
                    const ushort4 q = *(const ushort4*)(txt_stage + gnode * 96 + (k4 - 128));
                    v.x = bfu(q.x); v.y = bfu(q.y); v.z = bfu(q.z); v.w = bfu(q.w);
                } else if (k4 >= 64) {
                    const int c = k4 - 64;
                    f4v s = (f4v){0.f, 0.f, 0.f, 0.f};
                    #pragma unroll
                    for (int m = 0; m < 5; ++m) {
                        const f4v g = ld4(feat_table + (size_t)fiS[sr][m] * 64 + c);
                        s.x += g.x; s.y += g.y; s.z += g.z; s.w += g.w;
                    }
                    v.x = s.x * 0.2f; v.y = s.y * 0.2f;
                    v.z = s.z * 0.2f; v.w = s.w * 0.2f;
                } else {
                    v = ld4(id_emb + (size_t)srow * 64 + k4);
                }
            }
            vals[j] = v;
        }
    };

    const int NT = Kpad / 64;
    load_tile(0);
    for (int kt = 0; kt < NT; ++kt) {
        __syncthreads();   // previous tile's MFMA readers done
        #pragma unroll
        for (int j = 0; j < 2; ++j) {
            const f4v a0 = vals[2 * j], a1 = vals[2 * j + 1];
            uint4 pk;
            pk.x = pk2(a0.x, a0.y); pk.y = pk2(a0.z, a0.w);
            pk.z = pk2(a1.x, a1.y); pk.w = pk2(a1.z, a1.w);
            *(uint4*)&aS[sr][scq + j * 8] = pk;
        }
        __syncthreads();   // tile visible
        if (kt + 1 < NT) load_tile(kt + 1);   // prefetch, hidden under MFMA
        #pragma unroll
        for (int ks = 0; ks < 2; ++ks) {
            const bf16x8 af = *(const bf16x8*)&aS[w16 + l15][ks * 32 + hi8];
            #pragma unroll
            for (int ct = 0; ct < 4; ++ct) {
                const bf16x8 bfr = *(const bf16x8*)&WT[(size_t)(ct * 16 + l15) * Kpad
                                                      + kt * 64 + ks * 32 + hi8];
                acc[ct] = __builtin_amdgcn_mfma_f32_16x16x32_bf16(af, bfr, acc[ct], 0, 0, 0);
            }
        }
    }

    // epilogue: proj bias + numeric side-GEMM + num bias, write bf16 (cached)
    #pragma unroll
    for (int ct = 0; ct < 4; ++ct) {
        const int c = ct * 16 + l15;
        const float pb = projb[c] + numb[c];
        float wn[10];
        #pragma unroll
        for (int m = 0; m < 10; ++m) wn[m] = numW[m * 64 + c];
        #pragma unroll
        for (int j = 0; j < 4; ++j) {
            const int r = w16 + g4 + j;
            const int row = row0 + r;
            if (row < n) {
                float s = acc[ct][j] + pb;
                #pragma unroll
                for (int m = 0; m < 10; ++m) s += nmrS[r][m] * wn[m];
                x_out[(size_t)(row_off + row) * 64 + c] = bf16r(s);
            }
        }
    }
}

// ---------------------------------------------------------------------------
// GNN layer via MFMA. 64 rows/block. (unchanged from the 591us R3 config)
// ---------------------------------------------------------------------------
__global__ __launch_bounds__(256, 6) void gnn_layer_kernel(
    const unsigned short* __restrict__ x, const int* __restrict__ nbr,
    const unsigned short* __restrict__ VT, const unsigned short* __restrict__ W2T,
    const float* __restrict__ vb, const float* __restrict__ wb,
    void* __restrict__ outp, int finalize)
{
    __shared__ __align__(16) unsigned short mS[64][72];
    __shared__ int nbs[64][8];
    const int t = threadIdx.x;
    const int row0 = blockIdx.x * 64;

    for (int e = t; e < 512; e += 256) nbs[e >> 3][e & 7] = nbr[row0 * 8 + e];
    __syncthreads();

    {   // neighbor mean -> mS (bf16)
        const int r = t >> 2, c16 = (t & 3) * 16;
        float s[16];
        #pragma unroll
        for (int i = 0; i < 16; ++i) s[i] = 0.f;
        #pragma unroll
        for (int m = 0; m < 8; ++m) {
            const unsigned short* p = x + (size_t)nbs[r][m] * 64 + c16;
            const uint4 q0 = *(const uint4*)p;
            const uint4 q1 = *(const uint4*)(p + 8);
            s[0] += bfu(q0.x & 0xffff); s[1] += bfu(q0.x >> 16);
            s[2] += bfu(q0.y & 0xffff); s[3] += bfu(q0.y >> 16);
            s[4] += bfu(q0.z & 0xffff); s[5] += bfu(q0.z >> 16);
            s[6] += bfu(q0.w & 0xffff); s[7] += bfu(q0.w >> 16);
            s[8] += bfu(q1.x & 0xffff); s[9] += bfu(q1.x >> 16);
            s[10] += bfu(q1.y & 0xffff); s[11] += bfu(q1.y >> 16);
            s[12] += bfu(q1.z & 0xffff); s[13] += bfu(q1.z >> 16);
            s[14] += bfu(q1.w & 0xffff); s[15] += bfu(q1.w >> 16);
        }
        uint4 o0, o1;
        o0.x = pk2(s[0] * 0.125f, s[1] * 0.125f);
        o0.y = pk2(s[2] * 0.125f, s[3] * 0.125f);
        o0.z = pk2(s[4] * 0.125f, s[5] * 0.125f);
        o0.w = pk2(s[6] * 0.125f, s[7] * 0.125f);
        o1.x = pk2(s[8] * 0.125f, s[9] * 0.125f);
        o1.y = pk2(s[10] * 0.125f, s[11] * 0.125f);
        o1.z = pk2(s[12] * 0.125f, s[13] * 0.125f);
        o1.w = pk2(s[14] * 0.125f, s[15] * 0.125f);
        *(uint4*)&mS[r][c16] = o0;
        *(uint4*)&mS[r][c16 + 8] = o1;
    }
    __syncthreads();

    const int lane = t & 63;
    const int w16 = (t >> 6) * 16;
    const int l15 = lane & 15;
    const int hi8 = (lane >> 4) * 8;
    const int g4  = (lane >> 4) * 4;

    // agg = nm @ vW
    f32x4 ag[4];
    #pragma unroll
    for (int ct = 0; ct < 4; ++ct) ag[ct] = (f32x4){0.f, 0.f, 0.f, 0.f};
    #pragma unroll
    for (int ks = 0; ks < 2; ++ks) {
        const bf16x8 af = *(const bf16x8*)&mS[w16 + l15][ks * 32 + hi8];
        #pragma unroll
        for (int ct = 0; ct < 4; ++ct) {
            const bf16x8 bfr = *(const bf16x8*)&VT[(ct * 16 + l15) * 64 + ks * 32 + hi8];
            ag[ct] = __builtin_amdgcn_mfma_f32_16x16x32_bf16(af, bfr, ag[ct], 0, 0, 0);
        }
    }
    __syncthreads();   // nm readers done
    #pragma unroll
    for (int ct = 0; ct < 4; ++ct) {
        const int c = ct * 16 + l15;
        const float b = vb[c];
        #pragma unroll
        for (int j = 0; j < 4; ++j)
            mS[w16 + g4 + j][c] = bf16r(ag[ct][j] + b);
    }
    __syncthreads();

    // out = [x | ag] @ wW
    f32x4 acc[4];
    #pragma unroll
    for (int ct = 0; ct < 4; ++ct) acc[ct] = (f32x4){0.f, 0.f, 0.f, 0.f};
    #pragma unroll
    for (int ks = 0; ks < 4; ++ks) {
        bf16x8 af;
        if (ks < 2) af = *(const bf16x8*)&x[(size_t)(row0 + w16 + l15) * 64 + ks * 32 + hi8];
        else        af = *(const bf16x8*)&mS[w16 + l15][(ks - 2) * 32 + hi8];
        #pragma unroll
        for (int ct = 0; ct < 4; ++ct) {
            const bf16x8 bfr = *(const bf16x8*)&W2T[(ct * 16 + l15) * 128 + ks * 32 + hi8];
            acc[ct] = __builtin_amdgcn_mfma_f32_16x16x32_bf16(af, bfr, acc[ct], 0, 0, 0);
        }
    }

    if (!finalize) {
        unsigned short* xo = (unsigned short*)outp;
        #pragma unroll
        for (int ct = 0; ct < 4; ++ct) {
            const int c = ct * 16 + l15;
            const float b = wb[c];
            #pragma unroll
            for (int j = 0; j < 4; ++j)
                xo[(size_t)(row0 + w16 + g4 + j) * 64 + c] = bf16r(fmaxf(acc[ct][j] + b, 0.f));
        }
    } else {
        float* fo = (float*)outp;
        float vc[4][4], ss[4];
        #pragma unroll
        for (int j = 0; j < 4; ++j) ss[j] = 0.f;
        #pragma unroll
        for (int ct = 0; ct < 4; ++ct) {
            const float b = wb[ct * 16 + l15];
            #pragma unroll
            for (int j = 0; j < 4; ++j) {
                vc[ct][j] = acc[ct][j] + b;
                ss[j] += vc[ct][j] * vc[ct][j];
            }
        }
        #pragma unroll
        for (int m = 1; m < 16; m <<= 1) {
            #pragma unroll
            for (int j = 0; j < 4; ++j) ss[j] += __shfl_xor(ss[j], m, 64);
        }
        #pragma unroll
        for (int j = 0; j < 4; ++j) ss[j] = 1.f / fmaxf(sqrtf(ss[j]), 1e-12f);
        #pragma unroll
        for (int ct = 0; ct < 4; ++ct) {
            const int c = ct * 16 + l15;
            #pragma unroll
            for (int j = 0; j < 4; ++j)
                fo[(size_t)(row0 + w16 + g4 + j) * 64 + c] = vc[ct][j] * ss[j];
        }
    }
}

extern "C" void kernel_launch(void* const* d_in, const int* in_sizes, int n_in,
                              void* d_out, int out_size, void* d_ws, size_t ws_size,
                              hipStream_t stream) {
    const float* user_id_emb        = (const float*)d_in[0];
    const float* item_id_emb        = (const float*)d_in[1];
    const float* user_feat_table    = (const float*)d_in[2];
    const float* item_feat_table    = (const float*)d_in[3];
    const float* word_emb           = (const float*)d_in[4];
    const float* user_numeric       = (const float*)d_in[5];
    const float* item_numeric       = (const float*)d_in[6];
    const float* user_word_embedding= (const float*)d_in[7];
    const float* item_word_embedding= (const float*)d_in[8];
    const float* item_sentence_emb  = (const float*)d_in[9];
    const float* user_num_W         = (const float*)d_in[10];
    const float* user_num_b         = (const float*)d_in[11];
    const float* item_num_W         = (const float*)d_in[12];
    const float* item_num_b         = (const float*)d_in[13];
    const float* user_proj_W        = (const float*)d_in[14];
    const float* user_proj_b        = (const float*)d_in[15];
    const float* item_proj_W        = (const float*)d_in[16];
    const float* item_proj_b        = (const float*)d_in[17];
    const float* w_W                = (const float*)d_in[18];
    const float* w_b                = (const float*)d_in[19];
    const float* v_W                = (const float*)d_in[20];
    const float* v_b                = (const float*)d_in[21];
    const int*   user_feat_idx      = (const int*)d_in[22];
    const int*   item_feat_idx      = (const int*)d_in[23];
    const int*   user_text_idx      = (const int*)d_in[24];
    const int*   item_text_idx      = (const int*)d_in[25];
    const int*   neighbors          = (const int*)d_in[26];

    // ws layout (bf16): x0 [NTOT][64], x1 [NTOT][64]
    unsigned short* x0 = (unsigned short*)d_ws;
    unsigned short* x1 = x0 + (size_t)NTOT * 64;

    // d_out FRONT: text-mean staging [NTOT][96] bf16 (38.4 MB, consumed by
    // node_init before the final layer overwrites d_out)
    unsigned short* txt_stage = (unsigned short*)d_out;
    // d_out TAIL: bf16 weights (R3-proven placement, 270 KB)
    const size_t prep_bytes = 2ull * 64 * (KUP + KIP + 64 + 128);
    char* WTbase = (char*)d_out + (size_t)out_size * 4 - prep_bytes;
    unsigned short* WTu = (unsigned short*)WTbase;
    unsigned short* WTi = WTu + 64 * KUP;
    unsigned short* VT0 = WTi + 64 * KIP;
    unsigned short* W20 = VT0 + 64 * 64;
    // layer-1 weights re-prepped into dead x0 region after L0
    unsigned short* VT1 = (unsigned short*)d_ws;
    unsigned short* W21 = VT1 + 64 * 64;

    prep_wt<<<dim3((KUP + 255) / 256, 64), 256, 0, stream>>>(user_proj_W, WTu, KU, KUP);
    prep_wt<<<dim3((KIP + 255) / 256, 64), 256, 0, stream>>>(item_proj_W, WTi, KI, KIP);
    prep_wt<<<dim3(1, 64), 256, 0, stream>>>(v_W, VT0, 64, 64);
    prep_wt<<<dim3(1, 64), 256, 0, stream>>>(w_W, W20, 128, 128);

    // text-mean pre-pass (wave-per-node coalesced gather)
    txt_mean_kernel<<<NTOT / 4, 256, 0, stream>>>(
        word_emb, user_text_idx, item_text_idx, txt_stage);

    node_init_kernel<<<(NU + 63) / 64, 256, 0, stream>>>(
        user_id_emb, user_feat_table, txt_stage, user_numeric,
        user_word_embedding, nullptr, user_feat_idx,
        WTu, user_proj_b, user_num_W, user_num_b, x0, NU, KU, KUP, 0);
    node_init_kernel<<<(NI + 63) / 64, 256, 0, stream>>>(
        item_id_emb, item_feat_table, txt_stage, item_numeric,
        item_word_embedding, item_sentence_emb, item_feat_idx,
        WTi, item_proj_b, item_num_W, item_num_b, x0, NI, KI, KIP, NU);

    // layer 0: x0 -> x1 (relu, bf16)
    gnn_layer_kernel<<<NTOT / 64, 256, 0, stream>>>(
        x0, neighbors, VT0, W20, v_b, w_b, x1, 0);

    // re-prep layer-1 weights into dead x0 region
    prep_wt<<<dim3(1, 64), 256, 0, stream>>>(v_W + 64 * 64, VT1, 64, 64);
    prep_wt<<<dim3(1, 64), 256, 0, stream>>>(w_W + 128 * 64, W21, 128, 128);

    // layer 1 + fused normalize: x1 -> d_out (fp32, overwrites staging+weights)
    gnn_layer_kernel<<<NTOT / 64, 256, 0, stream>>>(
        x1, neighbors, VT1, W21, v_b + 64, w_b + 64, d_out, 1);
}